// Round 1
// baseline (224398.291 us; speedup 1.0000x reference)
//
#include <hip/hip_runtime.h>
#include <hip/hip_bf16.h>
#include <cstddef>

#define B     32
#define TENC  200
#define E     512
#define D     1024
#define P     256
#define M     80
#define TDEC  600
#define A     128
#define LF    32
#define KC    31
#define PAD   15

// output offsets (floats)
#define SPEC_OFF  0
#define STOP_OFF  ((size_t)B * TDEC * M)                       // 1,536,000
#define ALIGN_OFF (STOP_OFF + (size_t)B * TDEC)                // 1,555,200

// workspace layout (floats)
constexpr size_t N_PRET  = (size_t)TDEC * P * B;               // 4,915,200
constexpr size_t N_PM    = (size_t)B * TENC * A;               //   819,200
constexpr size_t OFF_PRET  = 0;
constexpr size_t OFF_PM    = OFF_PRET + N_PRET;
constexpr size_t OFF_HA0   = OFF_PM + N_PM;
constexpr size_t OFF_HA1   = OFF_HA0 + (size_t)D * B;
constexpr size_t OFF_CA    = OFF_HA1 + (size_t)D * B;
constexpr size_t OFF_HG0   = OFF_CA  + (size_t)D * B;
constexpr size_t OFF_HG1   = OFF_HG0 + (size_t)D * B;
constexpr size_t OFF_CG    = OFF_HG1 + (size_t)D * B;
constexpr size_t OFF_CTX   = OFF_CG  + (size_t)D * B;
constexpr size_t OFF_WPREV = OFF_CTX + (size_t)E * B;
constexpr size_t OFF_WCUM  = OFF_WPREV + (size_t)B * TENC;
constexpr size_t N_STATE   = 6 * (size_t)D * B + (size_t)E * B + 2 * (size_t)B * TENC;

__device__ __forceinline__ float sigmoidf(float x) { return 1.0f / (1.0f + expf(-x)); }

// ---------------------------------------------------------------------------
// Prenet: tgt[b,t,:] = (t==0 ? 0 : target[b,:,t-1]); two relu-dense layers.
// Writes preT[t][j][b]  (transposed for step-kernel coalescing).
__global__ __launch_bounds__(256) void prenet_kernel(
    const float* __restrict__ target, const float* __restrict__ W1, const float* __restrict__ b1,
    const float* __restrict__ W2, const float* __restrict__ b2, float* __restrict__ preT)
{
  const int t = blockIdx.x;
  const int tid = threadIdx.x;
  __shared__ float tg[B][M];
  __shared__ float x1[B][P];
  for (int i = tid; i < B * M; i += 256) {
    int b = i / M, m = i - b * M;
    tg[b][m] = (t == 0) ? 0.0f : target[(size_t)b * M * TDEC + (size_t)m * TDEC + (t - 1)];
  }
  __syncthreads();
  for (int i = tid; i < B * P; i += 256) {
    int b = i >> 8, j = i & 255;
    const float* w = W1 + (size_t)j * M;
    float acc = b1[j];
    for (int m = 0; m < M; ++m) acc += w[m] * tg[b][m];
    x1[b][j] = fmaxf(acc, 0.0f);
  }
  __syncthreads();
  for (int i = tid; i < B * P; i += 256) {
    int b = i >> 8, j = i & 255;
    const float* w = W2 + (size_t)j * P;
    float acc = b2[j];
    for (int m = 0; m < P; m += 4)
      acc += w[m]*x1[b][m] + w[m+1]*x1[b][m+1] + w[m+2]*x1[b][m+2] + w[m+3]*x1[b][m+3];
    preT[(size_t)t * P * B + (size_t)j * B + b] = fmaxf(acc, 0.0f);
  }
}

// ---------------------------------------------------------------------------
// proc_mem[b][t][a] = sum_k enc[b,t,k] * Wm[a,k]
__global__ __launch_bounds__(256) void procmem_kernel(
    const float* __restrict__ enc, const float* __restrict__ Wm, float* __restrict__ pm)
{
  const int blk = blockIdx.x;
  const int b = blk >> 3;
  const int t0 = (blk & 7) * 25;
  for (int i = threadIdx.x; i < 25 * A; i += 256) {
    int tl = i >> 7, a = i & 127;
    int t = t0 + tl;
    const float* x = enc + ((size_t)b * TENC + t) * E;
    const float* w = Wm + (size_t)a * E;
    float acc = 0.0f;
    for (int k = 0; k < E; k += 4)
      acc += w[k]*x[k] + w[k+1]*x[k+1] + w[k+2]*x[k+2] + w[k+3]*x[k+3];
    pm[((size_t)b * TENC + t) * A + a] = acc;
  }
}

// ---------------------------------------------------------------------------
// frame/stop projection for step ft (reads h_gen_ft laid out [d][b], ctx [e][b])
__device__ void frame_compute(int ft, int fb,
    const float* __restrict__ hG, const float* __restrict__ ctxT,
    const float* __restrict__ frame_W, const float* __restrict__ frame_b,
    const float* __restrict__ stop_W, const float* __restrict__ stop_b, float* __restrict__ out)
{
  int idx = fb * 256 + (int)threadIdx.x;
  if (idx >= B * (M + 1)) return;
  int b = idx / (M + 1);
  int j = idx - b * (M + 1);
  const float* w;
  float acc;
  if (j < M) { w = frame_W + (size_t)j * (D + E); acc = frame_b[j]; }
  else       { w = stop_W;                        acc = stop_b[0]; }
  const float* xh = hG + b;
  for (int k = 0; k < D; k += 4)
    acc += w[k]*xh[k*B] + w[k+1]*xh[(k+1)*B] + w[k+2]*xh[(k+2)*B] + w[k+3]*xh[(k+3)*B];
  const float* w2 = w + D;
  const float* xc = ctxT + b;
  for (int k = 0; k < E; k += 4)
    acc += w2[k]*xc[k*B] + w2[k+1]*xc[(k+1)*B] + w2[k+2]*xc[(k+2)*B] + w2[k+3]*xc[(k+3)*B];
  if (j < M) out[SPEC_OFF + (size_t)b * TDEC * M + (size_t)ft * M + j] = acc;
  else       out[STOP_OFF + (size_t)b * TDEC + ft] = acc;
}

// ---------------------------------------------------------------------------
// Attention-LSTM gates + state update.  blocks 0..255: gates (32 b x 4 dj x 2 gate-halves),
// blocks 256..266: fused frame/stop for step t-1.
__global__ __launch_bounds__(256) void att_step_kernel(
    int t,
    const float* __restrict__ preT, const float* __restrict__ ctxT,
    const float* __restrict__ hA_prev, float* __restrict__ hA_new, float* __restrict__ cA,
    const float* __restrict__ Wih, const float* __restrict__ Whh, const float* __restrict__ bias,
    const float* __restrict__ hG_prev, const float* __restrict__ frame_W, const float* __restrict__ frame_b,
    const float* __restrict__ stop_W, const float* __restrict__ stop_b, float* __restrict__ out)
{
  if (blockIdx.x >= 256) {
    if (t > 0)
      frame_compute(t - 1, blockIdx.x - 256, hG_prev, ctxT, frame_W, frame_b, stop_W, stop_b, out);
    return;
  }
  const int tid = threadIdx.x;
  const int b = tid & 31;
  const int q = tid >> 5;
  const int djl = q & 3;
  const int h = q >> 2;                 // 0: rows i,f   1: rows g,o
  const int dj = blockIdx.x * 4 + djl;
  const int row0 = (h ? 2 * D : 0) + dj;
  const int row1 = (h ? 3 * D : D) + dj;
  float acc0 = bias[row0];
  float acc1 = bias[row1];
  {
    const float4* w0 = reinterpret_cast<const float4*>(Wih + (size_t)row0 * 768);
    const float4* w1 = reinterpret_cast<const float4*>(Wih + (size_t)row1 * 768);
    const float* xp = preT + (size_t)t * P * B + b;
    #pragma unroll 4
    for (int k4 = 0; k4 < 64; ++k4) {           // cols [0,256): prenet frame
      float4 a0 = w0[k4], a1 = w1[k4];
      float x0 = xp[(k4*4+0)*B], x1 = xp[(k4*4+1)*B], x2 = xp[(k4*4+2)*B], x3 = xp[(k4*4+3)*B];
      acc0 += a0.x*x0 + a0.y*x1 + a0.z*x2 + a0.w*x3;
      acc1 += a1.x*x0 + a1.y*x1 + a1.z*x2 + a1.w*x3;
    }
    const float* xc = ctxT + b;
    #pragma unroll 4
    for (int k4 = 0; k4 < 128; ++k4) {          // cols [256,768): context
      float4 a0 = w0[64+k4], a1 = w1[64+k4];
      float x0 = xc[(k4*4+0)*B], x1 = xc[(k4*4+1)*B], x2 = xc[(k4*4+2)*B], x3 = xc[(k4*4+3)*B];
      acc0 += a0.x*x0 + a0.y*x1 + a0.z*x2 + a0.w*x3;
      acc1 += a1.x*x0 + a1.y*x1 + a1.z*x2 + a1.w*x3;
    }
  }
  {
    const float4* u0 = reinterpret_cast<const float4*>(Whh + (size_t)row0 * D);
    const float4* u1 = reinterpret_cast<const float4*>(Whh + (size_t)row1 * D);
    const float* xh = hA_prev + b;
    #pragma unroll 4
    for (int k4 = 0; k4 < 256; ++k4) {          // recurrent
      float4 a0 = u0[k4], a1 = u1[k4];
      float x0 = xh[(k4*4+0)*B], x1 = xh[(k4*4+1)*B], x2 = xh[(k4*4+2)*B], x3 = xh[(k4*4+3)*B];
      acc0 += a0.x*x0 + a0.y*x1 + a0.z*x2 + a0.w*x3;
      acc1 += a1.x*x0 + a1.y*x1 + a1.z*x2 + a1.w*x3;
    }
  }
  __shared__ float s0[256], s1[256];
  s0[tid] = acc0; s1[tid] = acc1;
  __syncthreads();
  if (h == 0) {
    float gi = acc0, gf = acc1;
    float gg = s0[tid + 128], go = s1[tid + 128];
    float c  = cA[(size_t)dj * B + b];
    float cn = sigmoidf(gf) * c + sigmoidf(gi) * tanhf(gg);
    float hn = sigmoidf(go) * tanhf(cn);
    cA[(size_t)dj * B + b] = cn;
    hA_new[(size_t)dj * B + b] = hn;
  }
}

// ---------------------------------------------------------------------------
// Generator-LSTM gates + update.  Same layout, K = 1024(hA) + 512(ctx) + 1024(hG rec).
__global__ __launch_bounds__(256) void gen_step_kernel(
    const float* __restrict__ hA, const float* __restrict__ ctxT,
    const float* __restrict__ hG_prev, float* __restrict__ hG_new, float* __restrict__ cG,
    const float* __restrict__ Wih, const float* __restrict__ Whh, const float* __restrict__ bias)
{
  const int tid = threadIdx.x;
  const int b = tid & 31;
  const int q = tid >> 5;
  const int djl = q & 3;
  const int h = q >> 2;
  const int dj = blockIdx.x * 4 + djl;
  const int row0 = (h ? 2 * D : 0) + dj;
  const int row1 = (h ? 3 * D : D) + dj;
  float acc0 = bias[row0];
  float acc1 = bias[row1];
  {
    const float4* w0 = reinterpret_cast<const float4*>(Wih + (size_t)row0 * (D + E));
    const float4* w1 = reinterpret_cast<const float4*>(Wih + (size_t)row1 * (D + E));
    const float* xh = hA + b;
    #pragma unroll 4
    for (int k4 = 0; k4 < 256; ++k4) {          // cols [0,1024): h_att
      float4 a0 = w0[k4], a1 = w1[k4];
      float x0 = xh[(k4*4+0)*B], x1 = xh[(k4*4+1)*B], x2 = xh[(k4*4+2)*B], x3 = xh[(k4*4+3)*B];
      acc0 += a0.x*x0 + a0.y*x1 + a0.z*x2 + a0.w*x3;
      acc1 += a1.x*x0 + a1.y*x1 + a1.z*x2 + a1.w*x3;
    }
    const float* xc = ctxT + b;
    #pragma unroll 4
    for (int k4 = 0; k4 < 128; ++k4) {          // cols [1024,1536): context
      float4 a0 = w0[256+k4], a1 = w1[256+k4];
      float x0 = xc[(k4*4+0)*B], x1 = xc[(k4*4+1)*B], x2 = xc[(k4*4+2)*B], x3 = xc[(k4*4+3)*B];
      acc0 += a0.x*x0 + a0.y*x1 + a0.z*x2 + a0.w*x3;
      acc1 += a1.x*x0 + a1.y*x1 + a1.z*x2 + a1.w*x3;
    }
  }
  {
    const float4* u0 = reinterpret_cast<const float4*>(Whh + (size_t)row0 * D);
    const float4* u1 = reinterpret_cast<const float4*>(Whh + (size_t)row1 * D);
    const float* xg = hG_prev + b;
    #pragma unroll 4
    for (int k4 = 0; k4 < 256; ++k4) {          // recurrent
      float4 a0 = u0[k4], a1 = u1[k4];
      float x0 = xg[(k4*4+0)*B], x1 = xg[(k4*4+1)*B], x2 = xg[(k4*4+2)*B], x3 = xg[(k4*4+3)*B];
      acc0 += a0.x*x0 + a0.y*x1 + a0.z*x2 + a0.w*x3;
      acc1 += a1.x*x0 + a1.y*x1 + a1.z*x2 + a1.w*x3;
    }
  }
  __shared__ float s0[256], s1[256];
  s0[tid] = acc0; s1[tid] = acc1;
  __syncthreads();
  if (h == 0) {
    float gi = acc0, gf = acc1;
    float gg = s0[tid + 128], go = s1[tid + 128];
    float c  = cG[(size_t)dj * B + b];
    float cn = sigmoidf(gf) * c + sigmoidf(gi) * tanhf(gg);
    float hn = sigmoidf(go) * tanhf(cn);
    cG[(size_t)dj * B + b] = cn;
    hG_new[(size_t)dj * B + b] = hn;
  }
}

// ---------------------------------------------------------------------------
// Location-sensitive attention. One block per batch row.
__global__ __launch_bounds__(256) void attention_kernel(
    int t,
    const float* __restrict__ hA, const float* __restrict__ enc, const int* __restrict__ lens,
    const float* __restrict__ pm, const float* __restrict__ Wq, const float* __restrict__ lker,
    const float* __restrict__ Wloc, const float* __restrict__ v_att, const float* __restrict__ b_att,
    float* __restrict__ wprev, float* __restrict__ wcum, float* __restrict__ ctxT,
    float* __restrict__ out)
{
  const int b = blockIdx.x;
  const int tid = threadIdx.x;
  __shared__ float swp[TENC], swc[TENC];
  __shared__ float hq[D];
  __shared__ float ker[LF * 2 * KC];
  __shared__ float lf[LF][TENC];
  __shared__ float query[A];
  __shared__ float e_s[TENC];
  __shared__ float epart[TENC][4];
  __shared__ float red[8];

  for (int i = tid; i < TENC; i += 256) { swp[i] = wprev[b * TENC + i]; swc[i] = wcum[b * TENC + i]; }
  for (int i = tid; i < D; i += 256) hq[i] = hA[(size_t)i * B + b];
  for (int i = tid; i < LF * 2 * KC; i += 256) ker[i] = lker[i];
  __syncthreads();

  // 1D conv over [w_prev; w_cum], zero padding
  for (int i = tid; i < LF * TENC; i += 256) {
    int f = i / TENC, tt = i - f * TENC;
    const float* k0 = ker + f * (2 * KC);
    const float* k1 = k0 + KC;
    float acc = 0.0f;
    for (int k = 0; k < KC; ++k) {
      int tp = tt + k - PAD;
      if (tp >= 0 && tp < TENC) acc += k0[k] * swp[tp] + k1[k] * swc[tp];
    }
    lf[f][tt] = acc;
  }
  // query = hA[b] @ Wq.T  (+ b_att folded in)
  if (tid < A) {
    const float* w = Wq + (size_t)tid * D;
    float acc = b_att[tid];
    for (int d = 0; d < D; d += 4)
      acc += w[d]*hq[d] + w[d+1]*hq[d+1] + w[d+2]*hq[d+2] + w[d+3]*hq[d+3];
    query[tid] = acc;
  }
  __syncthreads();

  // energies: e[t] = sum_a tanh(query + pm + loc_proj) * v     (a split 4-way)
  const int qd = tid & 3, tl = tid >> 2;
  for (int tt = tl; tt < TENC; tt += 64) {
    const float* pmt = pm + ((size_t)b * TENC + tt) * A;
    float acc = 0.0f;
    const int a0 = qd * 32;
    for (int a = a0; a < a0 + 32; ++a) {
      const float* wl = Wloc + a * LF;
      float lp = 0.0f;
      #pragma unroll
      for (int f = 0; f < LF; ++f) lp += wl[f] * lf[f][tt];
      acc += tanhf(query[a] + pmt[a] + lp) * v_att[a];
    }
    epart[tt][qd] = acc;
  }
  __syncthreads();

  const int len = lens[b];
  float lmax = -3.0e38f;
  for (int tt = tid; tt < TENC; tt += 256) {
    float e = epart[tt][0] + epart[tt][1] + epart[tt][2] + epart[tt][3];
    e = (tt < len) ? e : -1.0e9f;
    e_s[tt] = e;
    lmax = fmaxf(lmax, e);
  }
  // block max
  {
    float v = lmax;
    for (int o = 32; o > 0; o >>= 1) v = fmaxf(v, __shfl_down(v, o, 64));
    if ((tid & 63) == 0) red[tid >> 6] = v;
  }
  __syncthreads();
  const float gmax = fmaxf(fmaxf(red[0], red[1]), fmaxf(red[2], red[3]));
  __syncthreads();
  float lsum = 0.0f;
  for (int tt = tid; tt < TENC; tt += 256) {
    float p = expf(e_s[tt] - gmax);
    e_s[tt] = p;
    lsum += p;
  }
  {
    float v = lsum;
    for (int o = 32; o > 0; o >>= 1) v += __shfl_down(v, o, 64);
    if ((tid & 63) == 0) red[tid >> 6] = v;
  }
  __syncthreads();
  const float inv = 1.0f / (red[0] + red[1] + red[2] + red[3]);
  __syncthreads();
  for (int tt = tid; tt < TENC; tt += 256) {
    float w = e_s[tt] * inv;
    e_s[tt] = w;
    wprev[b * TENC + tt] = w;
    wcum[b * TENC + tt] = swc[tt] + w;
    out[ALIGN_OFF + ((size_t)b * TDEC + t) * TENC + tt] = w;
  }
  __syncthreads();
  // context = w @ enc[b]
  for (int e0 = tid; e0 < E; e0 += 256) {
    const float* ep = enc + (size_t)b * TENC * E + e0;
    float acc = 0.0f;
    for (int tt = 0; tt < TENC; ++tt) acc += e_s[tt] * ep[(size_t)tt * E];
    ctxT[(size_t)e0 * B + b] = acc;
  }
}

// ---------------------------------------------------------------------------
__global__ __launch_bounds__(256) void final_frame_kernel(
    const float* __restrict__ hG, const float* __restrict__ ctxT,
    const float* __restrict__ frame_W, const float* __restrict__ frame_b,
    const float* __restrict__ stop_W, const float* __restrict__ stop_b, float* __restrict__ out)
{
  frame_compute(TDEC - 1, blockIdx.x, hG, ctxT, frame_W, frame_b, stop_W, stop_b, out);
}

// ---------------------------------------------------------------------------
extern "C" void kernel_launch(void* const* d_in, const int* in_sizes, int n_in,
                              void* d_out, int out_size, void* d_ws, size_t ws_size,
                              hipStream_t stream)
{
  const float* enc      = (const float*)d_in[0];
  const int*   lens     = (const int*)  d_in[1];
  const float* target   = (const float*)d_in[2];
  // d_in[3]: teacher_forcing_ratio (unused — ratio==1 and reference never reads it)
  const float* pW1      = (const float*)d_in[4];
  const float* pb1      = (const float*)d_in[5];
  const float* pW2      = (const float*)d_in[6];
  const float* pb2      = (const float*)d_in[7];
  const float* att_Wih  = (const float*)d_in[8];
  const float* att_Whh  = (const float*)d_in[9];
  const float* att_b    = (const float*)d_in[10];
  const float* gen_Wih  = (const float*)d_in[11];
  const float* gen_Whh  = (const float*)d_in[12];
  const float* gen_b    = (const float*)d_in[13];
  const float* Wq       = (const float*)d_in[14];
  const float* Wm       = (const float*)d_in[15];
  const float* lker     = (const float*)d_in[16];
  const float* Wloc     = (const float*)d_in[17];
  const float* v_att    = (const float*)d_in[18];
  const float* b_att    = (const float*)d_in[19];
  const float* frame_W  = (const float*)d_in[20];
  const float* frame_b  = (const float*)d_in[21];
  const float* stop_W   = (const float*)d_in[22];
  const float* stop_b   = (const float*)d_in[23];

  float* ws   = (float*)d_ws;
  float* preT = ws + OFF_PRET;
  float* pm   = ws + OFF_PM;
  float* hA[2] = { ws + OFF_HA0, ws + OFF_HA1 };
  float* cA   = ws + OFF_CA;
  float* hG[2] = { ws + OFF_HG0, ws + OFF_HG1 };
  float* cG   = ws + OFF_CG;
  float* ctx  = ws + OFF_CTX;
  float* wpr  = ws + OFF_WPREV;
  float* wcu  = ws + OFF_WCUM;
  float* outF = (float*)d_out;

  // zero all recurrent state (ws is poisoned 0xAA before every call)
  hipMemsetAsync((void*)(ws + OFF_HA0), 0, N_STATE * sizeof(float), stream);

  prenet_kernel <<<TDEC, 256, 0, stream>>>(target, pW1, pb1, pW2, pb2, preT);
  procmem_kernel<<<256, 256, 0, stream>>>(enc, Wm, pm);

  for (int t = 0; t < TDEC; ++t) {
    float* hA_w = hA[t & 1];       const float* hA_r = hA[(t + 1) & 1];
    float* hG_w = hG[t & 1];       const float* hG_r = hG[(t + 1) & 1];
    att_step_kernel<<<267, 256, 0, stream>>>(t, preT, ctx, hA_r, hA_w, cA,
                                             att_Wih, att_Whh, att_b,
                                             hG_r, frame_W, frame_b, stop_W, stop_b, outF);
    attention_kernel<<<32, 256, 0, stream>>>(t, hA_w, enc, lens, pm, Wq, lker, Wloc,
                                             v_att, b_att, wpr, wcu, ctx, outF);
    gen_step_kernel<<<256, 256, 0, stream>>>(hA_w, ctx, hG_r, hG_w, cG,
                                             gen_Wih, gen_Whh, gen_b);
  }
  final_frame_kernel<<<11, 256, 0, stream>>>(hG[(TDEC - 1) & 1], ctx,
                                             frame_W, frame_b, stop_W, stop_b, outF);
}

// Round 2
// 135793.945 us; speedup vs baseline: 1.6525x; 1.6525x over previous
//
#include <hip/hip_runtime.h>
#include <hip/hip_bf16.h>
#include <cstddef>

#define B     32
#define TENC  200
#define E     512
#define D     1024
#define P     256
#define M     80
#define TDEC  600
#define A     128
#define LF    32
#define KC    31
#define PAD   15

typedef __attribute__((ext_vector_type(8))) short short8;
typedef __attribute__((ext_vector_type(4))) float float4v;

// output offsets (floats)
#define SPEC_OFF  0
#define STOP_OFF  ((size_t)B * TDEC * M)
#define ALIGN_OFF (STOP_OFF + (size_t)B * TDEC)

// ---------------- workspace layout (float units) ----------------
constexpr size_t OFF_PM    = 0;                         // 819200 f
constexpr size_t OFF_PREB  = 819200;                    // bf16 600*32*256 -> 2457600 f
constexpr size_t OFF_PKA   = OFF_PREB + 2457600;        // bf16 4096*1792  -> 3670016 f
constexpr size_t OFF_PKG   = OFF_PKA + 3670016;         // bf16 4096*2560  -> 5242880 f
constexpr size_t OFF_STATE = OFF_PKG + 5242880;
// zeroed state region (offsets relative to OFF_STATE, float units)
constexpr size_t ST_HAF  = 0;        // 32768  hA fp32 [d][b]
constexpr size_t ST_CA   = 32768;    // 32768
constexpr size_t ST_HGF  = 65536;    // 32768  hG fp32 [d][b]
constexpr size_t ST_CG   = 98304;    // 32768
constexpr size_t ST_CTXT = 131072;   // 16384  ctx fp32 [e][b]
constexpr size_t ST_WPR  = 147456;   // 6400
constexpr size_t ST_WCU  = 153856;   // 6400
constexpr size_t ST_HAB0 = 160256;   // bf16 [b][1024] -> 16384 f
constexpr size_t ST_HAB1 = 176640;
constexpr size_t ST_HGB0 = 193024;
constexpr size_t ST_HGB1 = 209408;
constexpr size_t ST_CTXB = 225792;   // bf16 [b][512] -> 8192 f
constexpr size_t N_STATE = 233984;

__device__ __forceinline__ float sigmoidf(float x) { return 1.0f / (1.0f + expf(-x)); }

// ---------------------------------------------------------------------------
// Pack [Wih | Whh] rows into MFMA B-fragment layout, bf16.
// Packed row n' = blockN*16 + r ; r -> gate = r&3, dj = blockN*4 + (r>>2)
// orig row = gate*D + dj.  k-fragment: lane holds k = k0*32 + (lane>>4)*8 + j.
__global__ __launch_bounds__(256) void pack_kernel(
    const float* __restrict__ Wih, const float* __restrict__ Whh,
    int KX, int NK0, __hip_bfloat16* __restrict__ pk, int total)
{
  for (int idx = blockIdx.x * 256 + threadIdx.x; idx < total; idx += gridDim.x * 256) {
    int e    = idx & 511;
    int frag = idx >> 9;
    int k0   = frag % NK0;
    int bn   = frag / NK0;
    int lane = e >> 3, j = e & 7;
    int r    = lane & 15;
    int row  = (r & 3) * D + bn * 4 + (r >> 2);
    int k    = k0 * 32 + ((lane >> 4) << 3) + j;
    float v  = (k < KX) ? Wih[(size_t)row * KX + k] : Whh[(size_t)row * D + (k - KX)];
    pk[idx] = __float2bfloat16(v);
  }
}

// ---------------------------------------------------------------------------
// Prenet -> preB[t][b][256] bf16
__global__ __launch_bounds__(256) void prenet_kernel(
    const float* __restrict__ target, const float* __restrict__ W1, const float* __restrict__ b1,
    const float* __restrict__ W2, const float* __restrict__ b2, __hip_bfloat16* __restrict__ preB)
{
  const int t = blockIdx.x;
  const int tid = threadIdx.x;
  __shared__ float tg[B][M];
  __shared__ float x1[B][P];
  for (int i = tid; i < B * M; i += 256) {
    int b = i / M, m = i - b * M;
    tg[b][m] = (t == 0) ? 0.0f : target[(size_t)b * M * TDEC + (size_t)m * TDEC + (t - 1)];
  }
  __syncthreads();
  for (int i = tid; i < B * P; i += 256) {
    int b = i >> 8, j = i & 255;
    const float* w = W1 + (size_t)j * M;
    float acc = b1[j];
    for (int m = 0; m < M; ++m) acc += w[m] * tg[b][m];
    x1[b][j] = fmaxf(acc, 0.0f);
  }
  __syncthreads();
  for (int i = tid; i < B * P; i += 256) {
    int b = i >> 8, j = i & 255;
    const float* w = W2 + (size_t)j * P;
    float acc = b2[j];
    for (int m = 0; m < P; m += 4)
      acc += w[m]*x1[b][m] + w[m+1]*x1[b][m+1] + w[m+2]*x1[b][m+2] + w[m+3]*x1[b][m+3];
    preB[(size_t)t * (B * P) + (size_t)b * P + j] = __float2bfloat16(fmaxf(acc, 0.0f));
  }
}

// ---------------------------------------------------------------------------
__global__ __launch_bounds__(256) void procmem_kernel(
    const float* __restrict__ enc, const float* __restrict__ Wm, float* __restrict__ pm)
{
  const int blk = blockIdx.x;
  const int b = blk >> 3;
  const int t0 = (blk & 7) * 25;
  for (int i = threadIdx.x; i < 25 * A; i += 256) {
    int tl = i >> 7, a = i & 127;
    int t = t0 + tl;
    const float* x = enc + ((size_t)b * TENC + t) * E;
    const float* w = Wm + (size_t)a * E;
    float acc = 0.0f;
    for (int k = 0; k < E; k += 4)
      acc += w[k]*x[k] + w[k+1]*x[k+1] + w[k+2]*x[k+2] + w[k+3]*x[k+3];
    pm[((size_t)b * TENC + t) * A + a] = acc;
  }
}

// ---------------------------------------------------------------------------
// frame/stop projection (fp32) for step ft
__device__ void frame_compute(int ft, int fb,
    const float* __restrict__ hG, const float* __restrict__ ctxT,
    const float* __restrict__ frame_W, const float* __restrict__ frame_b,
    const float* __restrict__ stop_W, const float* __restrict__ stop_b, float* __restrict__ out)
{
  int idx = fb * 256 + (int)threadIdx.x;
  if (idx >= B * (M + 1)) return;
  int b = idx / (M + 1);
  int j = idx - b * (M + 1);
  const float* w;
  float acc;
  if (j < M) { w = frame_W + (size_t)j * (D + E); acc = frame_b[j]; }
  else       { w = stop_W;                        acc = stop_b[0]; }
  const float* xh = hG + b;
  for (int k = 0; k < D; k += 4)
    acc += w[k]*xh[k*B] + w[k+1]*xh[(k+1)*B] + w[k+2]*xh[(k+2)*B] + w[k+3]*xh[(k+3)*B];
  const float* w2 = w + D;
  const float* xc = ctxT + b;
  for (int k = 0; k < E; k += 4)
    acc += w2[k]*xc[k*B] + w2[k+1]*xc[(k+1)*B] + w2[k+2]*xc[(k+2)*B] + w2[k+3]*xc[(k+3)*B];
  if (j < M) out[SPEC_OFF + (size_t)b * TDEC * M + (size_t)ft * M + j] = acc;
  else       out[STOP_OFF + (size_t)b * TDEC + ft] = acc;
}

// ---------------------------------------------------------------------------
// MFMA gate kernel. Block = (blockN, mt): 16 packed gate rows x 16 batch.
// 4 waves split K. LDS-reduce, fused LSTM epilogue. Att variant carries
// 11 extra blocks that do the frame/stop projection for step t-1.
template<int NK0, int K0A, int K0B, int SA, int SB, int SC, bool IS_ATT>
__global__ __launch_bounds__(256) void gate_kernel(
    int t,
    const __hip_bfloat16* __restrict__ xa, const __hip_bfloat16* __restrict__ xb,
    const __hip_bfloat16* __restrict__ xc, const __hip_bfloat16* __restrict__ pk,
    const float* __restrict__ bias, float* __restrict__ cbuf,
    float* __restrict__ hf32, __hip_bfloat16* __restrict__ hbf,
    const float* __restrict__ hGf, const float* __restrict__ ctxT,
    const float* __restrict__ frame_W, const float* __restrict__ frame_b,
    const float* __restrict__ stop_W, const float* __restrict__ stop_b,
    float* __restrict__ out)
{
  if (IS_ATT && blockIdx.x >= 512) {
    if (t > 0)
      frame_compute(t - 1, blockIdx.x - 512, hGf, ctxT, frame_W, frame_b, stop_W, stop_b, out);
    return;
  }
  const int blockN = blockIdx.x >> 1;
  const int mt     = blockIdx.x & 1;
  const int tid  = threadIdx.x;
  const int lane = tid & 63;
  const int w    = tid >> 6;
  const int m_l  = lane & 15;
  const int m    = mt * 16 + m_l;
  const int kq   = ((lane >> 4) << 3);
  constexpr int NW = NK0 / 4;
  float4v acc = {0.f, 0.f, 0.f, 0.f};
  const short8* pb = (const short8*)pk + ((size_t)blockN * NK0 + w * NW) * 64 + lane;
  const __hip_bfloat16* xam = xa + (size_t)m * SA;
  const __hip_bfloat16* xbm = xb + (size_t)m * SB;
  const __hip_bfloat16* xcm = xc + (size_t)m * SC;
  #pragma unroll 2
  for (int i = 0; i < NW; ++i) {
    const int k0 = w * NW + i;
    const int k = k0 * 32 + kq;
    const __hip_bfloat16* ap;
    if (k0 < K0A)      ap = xam + k;
    else if (k0 < K0B) ap = xbm + (k - K0A * 32);
    else               ap = xcm + (k - K0B * 32);
    short8 av = *(const short8*)ap;
    short8 bv = pb[(size_t)i * 64];
    acc = __builtin_amdgcn_mfma_f32_16x16x32_bf16(av, bv, acc, 0, 0, 0);
  }
  __shared__ float red[4][64][4];
  red[w][lane][0] = acc[0]; red[w][lane][1] = acc[1];
  red[w][lane][2] = acc[2]; red[w][lane][3] = acc[3];
  __syncthreads();
  if (tid < 64) {
    const int dj_l = tid >> 4, m2 = tid & 15;
    const int mm = mt * 16 + m2;
    const int dj = blockN * 4 + dj_l;
    float g4[4];
    #pragma unroll
    for (int g = 0; g < 4; ++g) {
      const int ls = ((m2 >> 2) << 4) | (dj_l * 4 + g);
      const int rg = m2 & 3;
      g4[g] = red[0][ls][rg] + red[1][ls][rg] + red[2][ls][rg] + red[3][ls][rg]
            + bias[g * D + dj];
    }
    const float c  = cbuf[dj * B + mm];
    const float cn = sigmoidf(g4[1]) * c + sigmoidf(g4[0]) * tanhf(g4[2]);
    const float hn = sigmoidf(g4[3]) * tanhf(cn);
    cbuf[dj * B + mm] = cn;
    hf32[dj * B + mm] = hn;
    hbf[(size_t)mm * D + dj] = __float2bfloat16(hn);
  }
}

// ---------------------------------------------------------------------------
// Location-sensitive attention, one block per batch row, 512 threads.
__global__ __launch_bounds__(512) void attention_kernel(
    int t,
    const float* __restrict__ hA, const float* __restrict__ enc, const int* __restrict__ lens,
    const float* __restrict__ pm, const float* __restrict__ Wq, const float* __restrict__ lker,
    const float* __restrict__ Wloc, const float* __restrict__ v_att, const float* __restrict__ b_att,
    float* __restrict__ wprev, float* __restrict__ wcum, float* __restrict__ ctxT,
    __hip_bfloat16* __restrict__ ctxB, float* __restrict__ out)
{
  const int b = blockIdx.x;
  const int tid = threadIdx.x;
  __shared__ float swp[TENC], swc[TENC];
  __shared__ float hq[D];
  __shared__ float ker[LF * 2 * KC];
  __shared__ float lf[LF][TENC];
  __shared__ float query[A];
  __shared__ float e_s[TENC];
  __shared__ float epart[TENC][4];
  __shared__ float qpart[A][4];
  __shared__ float red[8];

  for (int i = tid; i < TENC; i += 512) { swp[i] = wprev[b * TENC + i]; swc[i] = wcum[b * TENC + i]; }
  for (int i = tid; i < D; i += 512) hq[i] = hA[(size_t)i * B + b];
  for (int i = tid; i < LF * 2 * KC; i += 512) ker[i] = lker[i];
  __syncthreads();

  // conv over [w_prev; w_cum]
  for (int i = tid; i < LF * TENC; i += 512) {
    int f = i / TENC, tt = i - f * TENC;
    const float* k0 = ker + f * (2 * KC);
    const float* k1 = k0 + KC;
    float acc = 0.0f;
    int lo = (tt < PAD) ? (PAD - tt) : 0;
    int hi = (tt > TENC - 1 - PAD) ? (TENC - 1 - tt + PAD + 1) : KC;
    for (int k = lo; k < hi; ++k) { int tp = tt + k - PAD; acc += k0[k] * swp[tp] + k1[k] * swc[tp]; }
    lf[f][tt] = acc;
  }
  // query partials: 4 threads per a
  {
    int a = tid >> 2, qk = tid & 3;
    const float* wq = Wq + (size_t)a * D + qk * 256;
    const float* h  = hq + qk * 256;
    float acc = 0.0f;
    for (int d = 0; d < 256; d += 4)
      acc += wq[d]*h[d] + wq[d+1]*h[d+1] + wq[d+2]*h[d+2] + wq[d+3]*h[d+3];
    qpart[a][qk] = acc;
  }
  __syncthreads();
  if (tid < A) query[tid] = qpart[tid][0] + qpart[tid][1] + qpart[tid][2] + qpart[tid][3] + b_att[tid];
  __syncthreads();

  // energies: (tt, a-quarter) per thread
  {
    int qd = tid & 3, tl = tid >> 2;
    for (int tt = tl; tt < TENC; tt += 128) {
      const float* pmt = pm + ((size_t)b * TENC + tt) * A;
      float acc = 0.0f;
      const int a0 = qd * 32;
      for (int a = a0; a < a0 + 32; ++a) {
        const float* wl = Wloc + a * LF;
        float lp = 0.0f;
        #pragma unroll
        for (int f = 0; f < LF; ++f) lp += wl[f] * lf[f][tt];
        acc += tanhf(query[a] + pmt[a] + lp) * v_att[a];
      }
      epart[tt][qd] = acc;
    }
  }
  __syncthreads();

  const int len = lens[b];
  float lmax = -3.0e38f;
  for (int tt = tid; tt < TENC; tt += 512) {
    float e = epart[tt][0] + epart[tt][1] + epart[tt][2] + epart[tt][3];
    e = (tt < len) ? e : -1.0e9f;
    e_s[tt] = e;
    lmax = fmaxf(lmax, e);
  }
  for (int o = 32; o > 0; o >>= 1) lmax = fmaxf(lmax, __shfl_down(lmax, o, 64));
  if ((tid & 63) == 0) red[tid >> 6] = lmax;
  __syncthreads();
  float gmax = red[0];
  for (int i = 1; i < 8; ++i) gmax = fmaxf(gmax, red[i]);
  __syncthreads();
  float lsum = 0.0f;
  for (int tt = tid; tt < TENC; tt += 512) {
    float p = expf(e_s[tt] - gmax);
    e_s[tt] = p;
    lsum += p;
  }
  for (int o = 32; o > 0; o >>= 1) lsum += __shfl_down(lsum, o, 64);
  if ((tid & 63) == 0) red[tid >> 6] = lsum;
  __syncthreads();
  float inv = 0.0f;
  for (int i = 0; i < 8; ++i) inv += red[i];
  inv = 1.0f / inv;
  for (int tt = tid; tt < TENC; tt += 512) {
    float wv = e_s[tt] * inv;
    e_s[tt] = wv;
    wprev[b * TENC + tt] = wv;
    wcum[b * TENC + tt] = swc[tt] + wv;
    out[ALIGN_OFF + ((size_t)b * TDEC + t) * TENC + tt] = wv;
  }
  __syncthreads();
  // context
  {
    int e0 = tid;
    const float* ep = enc + (size_t)b * TENC * E + e0;
    float acc = 0.0f;
    for (int tt = 0; tt < TENC; ++tt) acc += e_s[tt] * ep[(size_t)tt * E];
    ctxT[(size_t)e0 * B + b] = acc;
    ctxB[(size_t)b * E + e0] = __float2bfloat16(acc);
  }
}

// ---------------------------------------------------------------------------
__global__ __launch_bounds__(256) void final_frame_kernel(
    const float* __restrict__ hG, const float* __restrict__ ctxT,
    const float* __restrict__ frame_W, const float* __restrict__ frame_b,
    const float* __restrict__ stop_W, const float* __restrict__ stop_b, float* __restrict__ out)
{
  frame_compute(TDEC - 1, blockIdx.x, hG, ctxT, frame_W, frame_b, stop_W, stop_b, out);
}

// ---------------------------------------------------------------------------
extern "C" void kernel_launch(void* const* d_in, const int* in_sizes, int n_in,
                              void* d_out, int out_size, void* d_ws, size_t ws_size,
                              hipStream_t stream)
{
  const float* enc      = (const float*)d_in[0];
  const int*   lens     = (const int*)  d_in[1];
  const float* target   = (const float*)d_in[2];
  const float* pW1      = (const float*)d_in[4];
  const float* pb1      = (const float*)d_in[5];
  const float* pW2      = (const float*)d_in[6];
  const float* pb2      = (const float*)d_in[7];
  const float* att_Wih  = (const float*)d_in[8];
  const float* att_Whh  = (const float*)d_in[9];
  const float* att_b    = (const float*)d_in[10];
  const float* gen_Wih  = (const float*)d_in[11];
  const float* gen_Whh  = (const float*)d_in[12];
  const float* gen_b    = (const float*)d_in[13];
  const float* Wq       = (const float*)d_in[14];
  const float* Wm       = (const float*)d_in[15];
  const float* lker     = (const float*)d_in[16];
  const float* Wloc     = (const float*)d_in[17];
  const float* v_att    = (const float*)d_in[18];
  const float* b_att    = (const float*)d_in[19];
  const float* frame_W  = (const float*)d_in[20];
  const float* frame_b  = (const float*)d_in[21];
  const float* stop_W   = (const float*)d_in[22];
  const float* stop_b   = (const float*)d_in[23];

  float* ws = (float*)d_ws;
  float*           pm   = ws + OFF_PM;
  __hip_bfloat16*  preB = (__hip_bfloat16*)(ws + OFF_PREB);
  __hip_bfloat16*  pkA  = (__hip_bfloat16*)(ws + OFF_PKA);
  __hip_bfloat16*  pkG  = (__hip_bfloat16*)(ws + OFF_PKG);
  float* st   = ws + OFF_STATE;
  float* hAf  = st + ST_HAF;
  float* cA   = st + ST_CA;
  float* hGf  = st + ST_HGF;
  float* cG   = st + ST_CG;
  float* ctxT = st + ST_CTXT;
  float* wpr  = st + ST_WPR;
  float* wcu  = st + ST_WCU;
  __hip_bfloat16* hAB[2] = { (__hip_bfloat16*)(st + ST_HAB0), (__hip_bfloat16*)(st + ST_HAB1) };
  __hip_bfloat16* hGB[2] = { (__hip_bfloat16*)(st + ST_HGB0), (__hip_bfloat16*)(st + ST_HGB1) };
  __hip_bfloat16* ctxB   = (__hip_bfloat16*)(st + ST_CTXB);
  float* outF = (float*)d_out;

  hipMemsetAsync((void*)st, 0, N_STATE * sizeof(float), stream);

  pack_kernel<<<2048, 256, 0, stream>>>(att_Wih, att_Whh, 768, 56, pkA, 4096 * 1792);
  pack_kernel<<<2048, 256, 0, stream>>>(gen_Wih, gen_Whh, 1536, 80, pkG, 4096 * 2560);
  prenet_kernel<<<TDEC, 256, 0, stream>>>(target, pW1, pb1, pW2, pb2, preB);
  procmem_kernel<<<256, 256, 0, stream>>>(enc, Wm, pm);

  for (int t = 0; t < TDEC; ++t) {
    const int cur = t & 1, prev = (t + 1) & 1;
    // att LSTM: x = [pre_t(256) | ctx_prev(512) | hA_prev(1024)]
    gate_kernel<56, 8, 24, 256, 512, 1024, true><<<523, 256, 0, stream>>>(
        t, preB + (size_t)t * (B * P), ctxB, hAB[prev], pkA, att_b, cA, hAf, hAB[cur],
        hGf, ctxT, frame_W, frame_b, stop_W, stop_b, outF);
    attention_kernel<<<32, 512, 0, stream>>>(
        t, hAf, enc, lens, pm, Wq, lker, Wloc, v_att, b_att, wpr, wcu, ctxT, ctxB, outF);
    // gen LSTM: x = [hA_new(1024) | ctx_new(512) | hG_prev(1024)]
    gate_kernel<80, 32, 48, 1024, 512, 1024, false><<<512, 256, 0, stream>>>(
        t, hAB[cur], ctxB, hGB[prev], pkG, gen_b, cG, hGf, hGB[cur],
        nullptr, nullptr, nullptr, nullptr, nullptr, nullptr, nullptr);
  }
  final_frame_kernel<<<11, 256, 0, stream>>>(hGf, ctxT, frame_W, frame_b, stop_W, stop_b, outF);
}

// Round 3
// 121703.491 us; speedup vs baseline: 1.8438x; 1.1158x over previous
//
#include <hip/hip_runtime.h>
#include <hip/hip_bf16.h>
#include <cstddef>

#define B     32
#define TENC  200
#define E     512
#define D     1024
#define P     256
#define M     80
#define TDEC  600
#define A     128
#define KC    31
#define LF    32

typedef __attribute__((ext_vector_type(8))) short short8;
typedef __attribute__((ext_vector_type(4))) float float4v;

// output offsets (floats)
#define SPEC_OFF  0
#define STOP_OFF  ((size_t)B * TDEC * M)
#define ALIGN_OFF (STOP_OFF + (size_t)B * TDEC)

// ---------------- workspace layout (float units) ----------------
constexpr size_t OFF_PM   = 0;                     // 819200
constexpr size_t OFF_PREB = 819200;                // bf16 600*32*256 -> 2457600 f
constexpr size_t OFF_KEFF = 3276800;               // 7936
constexpr size_t OFF_EG   = 3284736;               // 12800
constexpr size_t OFF_ST   = 3297536;
// state (zeroed each call), offsets relative to OFF_ST:
constexpr size_t ST_HAF  = 0;        // 32768  hA fp32 [b][d]
constexpr size_t ST_HGF  = 32768;    // 32768  hG fp32 [d][b]
constexpr size_t ST_CTXF = 65536;    // 2 x 16384 ctx fp32 [e][b]
constexpr size_t ST_WPR  = 98304;    // 6400
constexpr size_t ST_WCU  = 104704;   // 6400
constexpr size_t ST_HAB0 = 111104;   // bf16 [b][1024] = 16384 f
constexpr size_t ST_HAB1 = 127488;
constexpr size_t ST_HGB0 = 143872;
constexpr size_t ST_HGB1 = 160256;
constexpr size_t ST_CTXB = 176640;   // bf16 [b][512] = 8192 f
constexpr size_t ST_BARS = 184832;   // 1024 f of barrier counters
constexpr size_t N_STATE = 185856;

// LDS layout (bytes)
constexpr int LDS_ATTW  = 0;          // 56*512*2 = 57344
constexpr int LDS_GENW  = 57344;      // 80*512*2 = 81920
constexpr int LDS_SC    = 139264;     // 4096 floats scratch (red / P1 / P2 union)
constexpr int LDS_CA    = 155648;     // 128 f
constexpr int LDS_CG    = 156160;     // 128 f
constexpr int SMEM_BYTES = 156672;

struct Params {
  const float* enc; const int* lens;
  const float *att_Wih, *att_Whh, *att_b, *gen_Wih, *gen_Whh, *gen_b;
  const float *Wq, *v_att, *b_att, *frame_W, *frame_b, *stop_W, *stop_b;
  const float *pm, *keff;
  const __hip_bfloat16* preB;
  float *eg, *hAf, *hGf, *ctxf, *wpr, *wcu;
  __hip_bfloat16 *hAb0, *hAb1, *hGb0, *hGb1, *ctxb;
  unsigned* bars;
  float* out;
};

__device__ __forceinline__ float sigmoidf(float x) { return 1.0f / (1.0f + expf(-x)); }

// ---------------------------------------------------------------------------
// two-level grid barrier: 16 groups of 16 blocks; monotonic counters.
__device__ __forceinline__ void gbar(const Params& p, int ep) {
  __syncthreads();
  if (threadIdx.x == 0) {
    __threadfence();   // release
    unsigned* grp = p.bars + ((blockIdx.x >> 4) << 5);
    unsigned old = atomicAdd(grp, 1u);
    if (old + 1u == (unsigned)ep * 16u) atomicAdd(p.bars + 768, 1u);
    while (__hip_atomic_load(p.bars + 768, __ATOMIC_RELAXED, __HIP_MEMORY_SCOPE_AGENT)
           < (unsigned)ep * 16u)
      __builtin_amdgcn_s_sleep(4);
    __threadfence();   // acquire
  }
  __syncthreads();
}

// ---------------------------------------------------------------------------
template<int NF, int C0, int C1, int SA, int SB, int SC>
__device__ __forceinline__ float4v run_gemm(
    const __hip_bfloat16* lw, int f0,
    const __hip_bfloat16* __restrict__ xa, const __hip_bfloat16* __restrict__ xb,
    const __hip_bfloat16* __restrict__ xc, int m, int lane)
{
  float4v acc = {0.f, 0.f, 0.f, 0.f};
  const int kq = (lane >> 4) << 3;
  #pragma unroll
  for (int i = 0; i < NF; ++i) {
    const int k0 = f0 + i;
    const int k  = k0 * 32 + kq;
    const __hip_bfloat16* ap =
        (k0 < C0) ? (xa + (size_t)m * SA + k)
      : (k0 < C1) ? (xb + (size_t)m * SB + (k - C0 * 32))
                  : (xc + (size_t)m * SC + (k - C1 * 32));
    short8 av = *(const short8*)ap;
    short8 bv = *(const short8*)(lw + ((size_t)k0 * 512 + (size_t)lane * 8));
    acc = __builtin_amdgcn_mfma_f32_16x16x32_bf16(av, bv, acc, 0, 0, 0);
  }
  return acc;
}

// ---------------------------------------------------------------------------
__device__ __forceinline__ void frame_out(const Params& p, int ft, int fb) {
  int idx = fb * 512 + (int)threadIdx.x;
  if (idx >= B * (M + 1)) return;
  int b = idx / (M + 1), j = idx - b * (M + 1);
  const float* w; float acc;
  if (j < M) { w = p.frame_W + (size_t)j * 1536; acc = p.frame_b[j]; }
  else       { w = p.stop_W;                     acc = p.stop_b[0]; }
  const float* hg = p.hGf + b;
  #pragma unroll 4
  for (int k = 0; k < D; ++k) acc += w[k] * hg[(size_t)k * B];
  const float* cf = p.ctxf + (size_t)(ft & 1) * (E * B) + b;
  const float* w2 = w + D;
  #pragma unroll 4
  for (int k = 0; k < E; ++k) acc += w2[k] * cf[(size_t)k * B];
  if (j < M) p.out[SPEC_OFF + (size_t)b * TDEC * M + (size_t)ft * M + j] = acc;
  else       p.out[STOP_OFF + (size_t)b * TDEC + ft] = acc;
}

// ---------------------------------------------------------------------------
__global__ void __launch_bounds__(512) persist_kernel(Params p) {
  extern __shared__ char smem[];
  __hip_bfloat16* attw = (__hip_bfloat16*)(smem + LDS_ATTW);
  __hip_bfloat16* genw = (__hip_bfloat16*)(smem + LDS_GENW);
  float* sc  = (float*)(smem + LDS_SC);
  float* cAl = (float*)(smem + LDS_CA);
  float* cGl = (float*)(smem + LDS_CG);
  const int tid  = threadIdx.x;
  const int blk  = blockIdx.x;
  const int lane = tid & 63;
  const int wv   = tid >> 6;
  int ep = 0;

  // ============ prolog: pack this block's weight slice into LDS ============
  for (int idx = tid; idx < 56 * 512; idx += 512) {
    int k0 = idx >> 9, e = idx & 511, ln = e >> 3, j = e & 7, r = ln & 15;
    int row = (r & 3) * D + blk * 4 + (r >> 2);
    int k = k0 * 32 + ((ln >> 4) << 3) + j;
    float v = (k < 768) ? p.att_Wih[(size_t)row * 768 + k]
                        : p.att_Whh[(size_t)row * D + (k - 768)];
    attw[idx] = __float2bfloat16(v);
  }
  for (int idx = tid; idx < 80 * 512; idx += 512) {
    int k0 = idx >> 9, e = idx & 511, ln = e >> 3, j = e & 7, r = ln & 15;
    int row = (r & 3) * D + blk * 4 + (r >> 2);
    int k = k0 * 32 + ((ln >> 4) << 3) + j;
    float v = (k < 1536) ? p.gen_Wih[(size_t)row * 1536 + k]
                         : p.gen_Whh[(size_t)row * D + (k - 1536)];
    genw[idx] = __float2bfloat16(v);
  }
  if (tid < 128) { cAl[tid] = 0.f; cGl[tid] = 0.f; }
  __syncthreads();

  // ============ pre-phase: att gates for t=0 (ctx=-0, hA=-0) ============
  {
    const int mt = wv & 1, kqi = wv >> 1;
    const int m = mt * 16 + (lane & 15);
    float4v aA = run_gemm<14, 8, 24, 256, 512, 1024>(attw, kqi * 14,
                     p.preB, p.ctxb, p.hAb1, m, lane);
    float* r = sc + ((((0 * 2 + mt) * 4 + kqi) * 64 + lane) << 2);
    r[0] = aA[0]; r[1] = aA[1]; r[2] = aA[2]; r[3] = aA[3];
    __syncthreads();
    if (tid < 128) {
      int dj_l = (tid >> 5) & 3, mm = tid & 31;
      int dj = blk * 4 + dj_l;
      int mt2 = mm >> 4, m2 = mm & 15;
      float g4[4];
      #pragma unroll
      for (int gate = 0; gate < 4; ++gate) {
        int ln = ((m2 >> 2) << 4) | (dj_l * 4 + gate);
        int rg = m2 & 3;
        float s = 0.f;
        #pragma unroll
        for (int kq = 0; kq < 4; ++kq)
          s += sc[((((0 * 2 + mt2) * 4 + kq) * 64 + ln) << 2) + rg];
        g4[gate] = s + p.att_b[gate * D + dj];
      }
      float c  = cAl[dj_l * 32 + mm];
      float cn = sigmoidf(g4[1]) * c + sigmoidf(g4[0]) * tanhf(g4[2]);
      float hn = sigmoidf(g4[3]) * tanhf(cn);
      cAl[dj_l * 32 + mm] = cn;
      p.hAf[(size_t)mm * D + dj] = hn;
      p.hAb0[(size_t)mm * D + dj] = __float2bfloat16(hn);
    }
  }
  gbar(p, ++ep);

  // ============ main loop ============
  for (int t = 0; t < TDEC; ++t) {
    // ---- P1: attention energies (8 blocks per batch row) ----
    {
      const int b = blk >> 3, oct = blk & 7;
      // padded wprev/wcum into LDS: sc[0..230)=swp_pad, sc[230..460)=swc_pad
      for (int i = tid; i < 230; i += 512) {
        sc[i]       = (i >= 15 && i < 215) ? p.wpr[b * TENC + (i - 15)] : 0.f;
        sc[230 + i] = (i >= 15 && i < 215) ? p.wcu[b * TENC + (i - 15)] : 0.f;
      }
      // query partials: sc[460..972), query sc[972..1100)
      {
        int a = tid >> 2, qk = tid & 3;
        const float* wq = p.Wq  + (size_t)a * D + qk * 256;
        const float* h  = p.hAf + (size_t)b * D + qk * 256;
        float acc = 0.f;
        for (int i = 0; i < 256; i += 4)
          acc += wq[i]*h[i] + wq[i+1]*h[i+1] + wq[i+2]*h[i+2] + wq[i+3]*h[i+3];
        sc[460 + a * 4 + qk] = acc;
      }
      __syncthreads();
      if (tid < A)
        sc[972 + tid] = sc[460 + tid*4] + sc[460 + tid*4 + 1]
                      + sc[460 + tid*4 + 2] + sc[460 + tid*4 + 3] + p.b_att[tid];
      __syncthreads();
      {
        const int ah = wv & 1, sub = wv >> 1;
        const int a = ah * 64 + lane;
        float k0r[KC], k1r[KC];
        #pragma unroll
        for (int k = 0; k < KC; ++k) {
          k0r[k] = p.keff[a * KC + k];
          k1r[k] = p.keff[A * KC + a * KC + k];
        }
        const float qv = sc[972 + a];
        const float vv = p.v_att[a];
        const int base = oct * 25;
        for (int tt = base + sub; tt < base + 25; tt += 4) {
          float lp = 0.f;
          #pragma unroll
          for (int k = 0; k < KC; ++k)
            lp += k0r[k] * sc[tt + k] + k1r[k] * sc[230 + tt + k];
          float ev = tanhf(qv + p.pm[((size_t)b * TENC + tt) * A + a] + lp) * vv;
          for (int o = 32; o > 0; o >>= 1) ev += __shfl_down(ev, o, 64);
          if (lane == 0) p.eg[((size_t)b * TENC + tt) * 2 + ah] = ev;
        }
      }
    }
    gbar(p, ++ep);

    // ---- P2: softmax + context (blocks 0..31), frame t-1 (blocks 64..69) ----
    if (blk < 32) {
      const int b = blk;
      const int len = p.lens[b];
      for (int i = tid; i < TENC; i += 512) {
        float e = p.eg[((size_t)b * TENC + i) * 2] + p.eg[((size_t)b * TENC + i) * 2 + 1];
        sc[i] = (i < len) ? e : -1.0e9f;
      }
      __syncthreads();
      float lm = -3.0e38f;
      for (int i = tid; i < TENC; i += 512) lm = fmaxf(lm, sc[i]);
      for (int o = 32; o > 0; o >>= 1) lm = fmaxf(lm, __shfl_down(lm, o, 64));
      if (lane == 0) sc[400 + wv] = lm;
      __syncthreads();
      float gm = sc[400];
      for (int i = 1; i < 8; ++i) gm = fmaxf(gm, sc[400 + i]);
      float ls = 0.f;
      for (int i = tid; i < TENC; i += 512) {
        float pp = expf(sc[i] - gm);
        sc[200 + i] = pp;
        ls += pp;
      }
      for (int o = 32; o > 0; o >>= 1) ls += __shfl_down(ls, o, 64);
      if (lane == 0) sc[408 + wv] = ls;
      __syncthreads();
      float inv = 0.f;
      for (int i = 0; i < 8; ++i) inv += sc[408 + i];
      inv = 1.0f / inv;
      for (int i = tid; i < TENC; i += 512) {
        float wval = sc[200 + i] * inv;
        sc[200 + i] = wval;
        p.wpr[b * TENC + i] = wval;
        p.wcu[b * TENC + i] += wval;
        p.out[ALIGN_OFF + ((size_t)b * TDEC + t) * TENC + i] = wval;
      }
      __syncthreads();
      {
        const float* ebase = p.enc + (size_t)b * TENC * E + tid;
        float acc = 0.f;
        #pragma unroll 4
        for (int tt = 0; tt < TENC; ++tt) acc += sc[200 + tt] * ebase[(size_t)tt * E];
        p.ctxf[(size_t)(t & 1) * (E * B) + (size_t)tid * B + b] = acc;
        p.ctxb[(size_t)b * E + tid] = __float2bfloat16(acc);
      }
    } else if (blk >= 64 && blk < 70) {
      if (t > 0) frame_out(p, t - 1, blk - 64);
    }
    gbar(p, ++ep);

    // ---- P3: gen gates t + att gates t+1 ----
    {
      const __hip_bfloat16* hAcur  = (t & 1) ? p.hAb1 : p.hAb0;
      __hip_bfloat16*       hAnxt  = (t & 1) ? p.hAb0 : p.hAb1;
      const __hip_bfloat16* hGprev = (t & 1) ? p.hGb0 : p.hGb1;
      __hip_bfloat16*       hGcur  = (t & 1) ? p.hGb1 : p.hGb0;
      const bool doatt = (t < TDEC - 1);
      const int mt = wv & 1, kqi = wv >> 1;
      const int m = mt * 16 + (lane & 15);
      if (doatt) {
        float4v aA = run_gemm<14, 8, 24, 256, 512, 1024>(attw, kqi * 14,
                         p.preB + (size_t)(t + 1) * (B * P), p.ctxb, hAcur, m, lane);
        float* r = sc + ((((0 * 2 + mt) * 4 + kqi) * 64 + lane) << 2);
        r[0] = aA[0]; r[1] = aA[1]; r[2] = aA[2]; r[3] = aA[3];
      }
      {
        float4v aG = run_gemm<20, 32, 48, 1024, 512, 1024>(genw, kqi * 20,
                         hAcur, p.ctxb, hGprev, m, lane);
        float* r = sc + ((((1 * 2 + mt) * 4 + kqi) * 64 + lane) << 2);
        r[0] = aG[0]; r[1] = aG[1]; r[2] = aG[2]; r[3] = aG[3];
      }
      __syncthreads();
      if (tid < 256) {
        const int g = tid >> 7, dj_l = (tid >> 5) & 3, mm = tid & 31;
        if (g == 1 || doatt) {
          const int dj = blk * 4 + dj_l;
          const int mt2 = mm >> 4, m2 = mm & 15;
          const float* bias = (g == 0) ? p.att_b : p.gen_b;
          float g4[4];
          #pragma unroll
          for (int gate = 0; gate < 4; ++gate) {
            int ln = ((m2 >> 2) << 4) | (dj_l * 4 + gate);
            int rg = m2 & 3;
            float s = 0.f;
            #pragma unroll
            for (int kq = 0; kq < 4; ++kq)
              s += sc[((((g * 2 + mt2) * 4 + kq) * 64 + ln) << 2) + rg];
            g4[gate] = s + bias[gate * D + dj];
          }
          float* cl = (g == 0) ? cAl : cGl;
          float c  = cl[dj_l * 32 + mm];
          float cn = sigmoidf(g4[1]) * c + sigmoidf(g4[0]) * tanhf(g4[2]);
          float hn = sigmoidf(g4[3]) * tanhf(cn);
          cl[dj_l * 32 + mm] = cn;
          if (g == 0) {
            p.hAf[(size_t)mm * D + dj] = hn;
            hAnxt[(size_t)mm * D + dj] = __float2bfloat16(hn);
          } else {
            p.hGf[(size_t)dj * B + mm] = hn;
            hGcur[(size_t)mm * D + dj] = __float2bfloat16(hn);
          }
        }
      }
    }
    gbar(p, ++ep);
  }

  // ---- final frame (t = 599) ----
  if (blk < 6) frame_out(p, TDEC - 1, blk);
}

// ---------------------------------------------------------------------------
// Prenet -> preB[t][b][256] bf16
__global__ __launch_bounds__(256) void prenet_kernel(
    const float* __restrict__ target, const float* __restrict__ W1, const float* __restrict__ b1,
    const float* __restrict__ W2, const float* __restrict__ b2, __hip_bfloat16* __restrict__ preB)
{
  const int t = blockIdx.x;
  const int tid = threadIdx.x;
  __shared__ float tg[B][M];
  __shared__ float x1[B][P];
  for (int i = tid; i < B * M; i += 256) {
    int b = i / M, m = i - b * M;
    tg[b][m] = (t == 0) ? 0.0f : target[(size_t)b * M * TDEC + (size_t)m * TDEC + (t - 1)];
  }
  __syncthreads();
  for (int i = tid; i < B * P; i += 256) {
    int b = i >> 8, j = i & 255;
    const float* w = W1 + (size_t)j * M;
    float acc = b1[j];
    for (int m = 0; m < M; ++m) acc += w[m] * tg[b][m];
    x1[b][j] = fmaxf(acc, 0.0f);
  }
  __syncthreads();
  for (int i = tid; i < B * P; i += 256) {
    int b = i >> 8, j = i & 255;
    const float* w = W2 + (size_t)j * P;
    float acc = b2[j];
    for (int m = 0; m < P; m += 4)
      acc += w[m]*x1[b][m] + w[m+1]*x1[b][m+1] + w[m+2]*x1[b][m+2] + w[m+3]*x1[b][m+3];
    preB[(size_t)t * (B * P) + (size_t)b * P + j] = __float2bfloat16(fmaxf(acc, 0.0f));
  }
}

// ---------------------------------------------------------------------------
__global__ __launch_bounds__(256) void procmem_kernel(
    const float* __restrict__ enc, const float* __restrict__ Wm, float* __restrict__ pm)
{
  const int blk = blockIdx.x;
  const int b = blk >> 3;
  const int t0 = (blk & 7) * 25;
  for (int i = threadIdx.x; i < 25 * A; i += 256) {
    int tl = i >> 7, a = i & 127;
    int t = t0 + tl;
    const float* x = enc + ((size_t)b * TENC + t) * E;
    const float* w = Wm + (size_t)a * E;
    float acc = 0.0f;
    for (int k = 0; k < E; k += 4)
      acc += w[k]*x[k] + w[k+1]*x[k+1] + w[k+2]*x[k+2] + w[k+3]*x[k+3];
    pm[((size_t)b * TENC + t) * A + a] = acc;
  }
}

// ---------------------------------------------------------------------------
// Keff[a][k] = sum_f Wloc[a,f] * loc_kernel[f, 0/1, k]
__global__ __launch_bounds__(256) void keff_kernel(
    const float* __restrict__ lker, const float* __restrict__ Wloc, float* __restrict__ keff)
{
  int idx = blockIdx.x * 256 + threadIdx.x;
  if (idx >= A * KC) return;
  int a = idx / KC, k = idx - a * KC;
  float s0 = 0.f, s1 = 0.f;
  for (int f = 0; f < LF; ++f) {
    float wl = Wloc[a * LF + f];
    s0 += wl * lker[f * (2 * KC) + k];
    s1 += wl * lker[f * (2 * KC) + KC + k];
  }
  keff[a * KC + k] = s0;
  keff[A * KC + a * KC + k] = s1;
}

// ---------------------------------------------------------------------------
extern "C" void kernel_launch(void* const* d_in, const int* in_sizes, int n_in,
                              void* d_out, int out_size, void* d_ws, size_t ws_size,
                              hipStream_t stream)
{
  const float* enc      = (const float*)d_in[0];
  const int*   lens     = (const int*)  d_in[1];
  const float* target   = (const float*)d_in[2];
  const float* pW1      = (const float*)d_in[4];
  const float* pb1      = (const float*)d_in[5];
  const float* pW2      = (const float*)d_in[6];
  const float* pb2      = (const float*)d_in[7];
  const float* att_Wih  = (const float*)d_in[8];
  const float* att_Whh  = (const float*)d_in[9];
  const float* att_b    = (const float*)d_in[10];
  const float* gen_Wih  = (const float*)d_in[11];
  const float* gen_Whh  = (const float*)d_in[12];
  const float* gen_b    = (const float*)d_in[13];
  const float* Wq       = (const float*)d_in[14];
  const float* Wm       = (const float*)d_in[15];
  const float* lker     = (const float*)d_in[16];
  const float* Wloc     = (const float*)d_in[17];
  const float* v_att    = (const float*)d_in[18];
  const float* b_att    = (const float*)d_in[19];
  const float* frame_W  = (const float*)d_in[20];
  const float* frame_b  = (const float*)d_in[21];
  const float* stop_W   = (const float*)d_in[22];
  const float* stop_b   = (const float*)d_in[23];

  float* ws = (float*)d_ws;
  float* st = ws + OFF_ST;

  Params p;
  p.enc = enc; p.lens = lens;
  p.att_Wih = att_Wih; p.att_Whh = att_Whh; p.att_b = att_b;
  p.gen_Wih = gen_Wih; p.gen_Whh = gen_Whh; p.gen_b = gen_b;
  p.Wq = Wq; p.v_att = v_att; p.b_att = b_att;
  p.frame_W = frame_W; p.frame_b = frame_b; p.stop_W = stop_W; p.stop_b = stop_b;
  p.pm   = ws + OFF_PM;
  p.keff = ws + OFF_KEFF;
  p.preB = (const __hip_bfloat16*)(ws + OFF_PREB);
  p.eg   = ws + OFF_EG;
  p.hAf  = st + ST_HAF;
  p.hGf  = st + ST_HGF;
  p.ctxf = st + ST_CTXF;
  p.wpr  = st + ST_WPR;
  p.wcu  = st + ST_WCU;
  p.hAb0 = (__hip_bfloat16*)(st + ST_HAB0);
  p.hAb1 = (__hip_bfloat16*)(st + ST_HAB1);
  p.hGb0 = (__hip_bfloat16*)(st + ST_HGB0);
  p.hGb1 = (__hip_bfloat16*)(st + ST_HGB1);
  p.ctxb = (__hip_bfloat16*)(st + ST_CTXB);
  p.bars = (unsigned*)(st + ST_BARS);
  p.out  = (float*)d_out;

  hipMemsetAsync((void*)st, 0, N_STATE * sizeof(float), stream);

  keff_kernel   <<<16, 256, 0, stream>>>(lker, Wloc, ws + OFF_KEFF);
  prenet_kernel <<<TDEC, 256, 0, stream>>>(target, pW1, pb1, pW2, pb2,
                                           (__hip_bfloat16*)(ws + OFF_PREB));
  procmem_kernel<<<256, 256, 0, stream>>>(enc, Wm, ws + OFF_PM);

  hipFuncSetAttribute((const void*)persist_kernel,
                      hipFuncAttributeMaxDynamicSharedMemorySize, SMEM_BYTES);
  persist_kernel<<<256, 512, SMEM_BYTES, stream>>>(p);
}

// Round 4
// 85211.005 us; speedup vs baseline: 2.6334x; 1.4283x over previous
//
#include <hip/hip_runtime.h>
#include <hip/hip_bf16.h>
#include <cstddef>

#define B     32
#define TENC  200
#define E     512
#define D     1024
#define P     256
#define M     80
#define TDEC  600
#define A     128
#define KC    31
#define LF    32

typedef __attribute__((ext_vector_type(8))) short short8;
typedef __attribute__((ext_vector_type(4))) float float4v;
typedef unsigned short u16;

// output offsets (floats)
#define SPEC_OFF  0
#define STOP_OFF  ((size_t)B * TDEC * M)
#define ALIGN_OFF (STOP_OFF + (size_t)B * TDEC)

// ---------------- workspace layout (float units) ----------------
constexpr size_t OFF_PM   = 0;                    // fp32 [b][t][a]   819200
constexpr size_t OFF_PREB = 819200;               // bf16 [t][b][256] 2457600 f
constexpr size_t OFF_KPK  = 3276800;              // bf16 packed keff 8192 -> 4096 f
constexpr size_t OFF_WQB  = 3280896;              // bf16 Wq 131072 -> 65536 f
constexpr size_t OFF_ST   = 3346432;
// state region (zeroed each call), float offsets relative to OFF_ST:
constexpr size_t ST_HAB0 = 0;       // bf16 [b][1024] -> 16384 f
constexpr size_t ST_HAB1 = 16384;
constexpr size_t ST_HGB0 = 32768;
constexpr size_t ST_HGB1 = 49152;
constexpr size_t ST_CTXB = 65536;   // bf16 [b][512] -> 8192 f
constexpr size_t ST_CTXF = 73728;   // fp32 2 x [b][512] -> 32768 f
constexpr size_t ST_HGF  = 106496;  // fp32 [b][1024] -> 32768 f
constexpr size_t ST_BARS = 139264;  // 1024 f barrier counters
constexpr size_t N_STATE = 140288;

// ---------------- LDS layout (bytes) ----------------
constexpr int LDS_ATTW = 0;          // 56*512*2  = 57344
constexpr int LDS_GENW = 57344;      // 80*512*2  = 81920
constexpr int LDS_SC   = 139264;     // 5184 floats scratch (20736 B)
constexpr int LDS_SP   = 160000;     // 232 f padded wprev
constexpr int LDS_SCM  = 160928;     // 232 f padded wcum
constexpr int LDS_CA   = 161856;     // 128 f
constexpr int LDS_CG   = 162368;     // 128 f
constexpr int SMEM_BYTES = 162880;   // <= 163840

struct Params {
  const float* enc; const int* lens;
  const float *att_Wih, *att_Whh, *att_b, *gen_Wih, *gen_Whh, *gen_b;
  const float *v_att, *b_att, *frame_W, *frame_b, *stop_W, *stop_b;
  const float *pm;
  const u16 *preB, *kpk, *wqb;
  u16 *hAb0, *hAb1, *hGb0, *hGb1, *ctxb;
  float *ctxf, *hGf;
  unsigned* bars;
  float* out;
};

__device__ __forceinline__ float sigmoidf(float x) { return 1.0f / (1.0f + expf(-x)); }
__device__ __forceinline__ u16 f2bf(float x) {
  __hip_bfloat16 h = __float2bfloat16(x);
  return __builtin_bit_cast(u16, h);
}
__device__ __forceinline__ float bf2f(u16 u) {
  unsigned v = ((unsigned)u) << 16;
  return __builtin_bit_cast(float, v);
}

// ---- MALL-coherent access helpers (bypass non-coherent per-XCD L2) ----
#define LDC(r, p) asm volatile("global_load_dwordx4 %0, %1, off sc0 sc1" : "=v"(r) : "v"(p))

__device__ __forceinline__ float4v ldc1(const void* p) {
  float4v r;
  LDC(r, p);
  asm volatile("s_waitcnt vmcnt(0)" : "+v"(r) :: "memory");
  return r;
}
__device__ __forceinline__ void stc_f32(float* p, float v) {
  asm volatile("global_store_dword %0, %1, off sc0 sc1" :: "v"(p), "v"(v) : "memory");
}
__device__ __forceinline__ void stc_u16(u16* p, u16 v) {
  unsigned vv = v;
  asm volatile("global_store_short %0, %1, off sc0 sc1" :: "v"(p), "v"(vv) : "memory");
}

// ---------------------------------------------------------------------------
// grid barrier WITHOUT agent-scope fences (no L2 invalidate!).  All data
// communicated between blocks goes through sc0/sc1 (MALL-coherent) accesses,
// so the only ordering needed is: stores drained (syncthreads does vmcnt(0))
// before the device-scope atomic signal.
__device__ __forceinline__ void gbar(unsigned* bars, int ep) {
  __syncthreads();
  if (threadIdx.x == 0) {
    unsigned* grp = bars + ((blockIdx.x >> 4) << 5);
    unsigned old = atomicAdd(grp, 1u);
    if (old + 1u == (unsigned)ep * 16u) atomicAdd(bars + 768, 1u);
    while (__hip_atomic_load(bars + 768, __ATOMIC_RELAXED, __HIP_MEMORY_SCOPE_AGENT)
           < (unsigned)ep * 16u)
      __builtin_amdgcn_s_sleep(2);
  }
  __syncthreads();
}

// ---------------------------------------------------------------------------
// 16-row-tile MFMA gemm with coherent batched A loads.  lw = LDS B-fragments.
#define GMF(i) acc = __builtin_amdgcn_mfma_f32_16x16x32_bf16( \
    __builtin_bit_cast(short8, aa##i), \
    *(const short8*)(lw + ((size_t)(f0 + i) * 512 + (size_t)lane * 8)), acc, 0, 0, 0)

template<int C0, int C1, int SA, int SB, int SC>
__device__ __forceinline__ float4v gemm14(const __hip_bfloat16* lw, int f0,
    const u16* xa, const u16* xb, const u16* xc, int m, int lane)
{
  const int kq = (lane >> 4) << 3;
  auto sel = [&](int k0) -> const void* {
    int k = k0 * 32 + kq;
    if (k0 < C0) return (const void*)(xa + (size_t)m * SA + k);
    if (k0 < C1) return (const void*)(xb + (size_t)m * SB + (k - C0 * 32));
    return (const void*)(xc + (size_t)m * SC + (k - C1 * 32));
  };
  float4v aa0,aa1,aa2,aa3,aa4,aa5,aa6,aa7,aa8,aa9,aa10,aa11,aa12,aa13;
  LDC(aa0,sel(f0+0)); LDC(aa1,sel(f0+1)); LDC(aa2,sel(f0+2)); LDC(aa3,sel(f0+3));
  LDC(aa4,sel(f0+4)); LDC(aa5,sel(f0+5)); LDC(aa6,sel(f0+6)); LDC(aa7,sel(f0+7));
  LDC(aa8,sel(f0+8)); LDC(aa9,sel(f0+9)); LDC(aa10,sel(f0+10)); LDC(aa11,sel(f0+11));
  LDC(aa12,sel(f0+12)); LDC(aa13,sel(f0+13));
  asm volatile("s_waitcnt vmcnt(0)"
    : "+v"(aa0),"+v"(aa1),"+v"(aa2),"+v"(aa3),"+v"(aa4),"+v"(aa5),"+v"(aa6),
      "+v"(aa7),"+v"(aa8),"+v"(aa9),"+v"(aa10),"+v"(aa11),"+v"(aa12),"+v"(aa13)
    :: "memory");
  float4v acc = {0.f, 0.f, 0.f, 0.f};
  GMF(0); GMF(1); GMF(2); GMF(3); GMF(4); GMF(5); GMF(6);
  GMF(7); GMF(8); GMF(9); GMF(10); GMF(11); GMF(12); GMF(13);
  return acc;
}

template<int C0, int C1, int SA, int SB, int SC>
__device__ __forceinline__ float4v gemm20(const __hip_bfloat16* lw, int f0,
    const u16* xa, const u16* xb, const u16* xc, int m, int lane)
{
  const int kq = (lane >> 4) << 3;
  auto sel = [&](int k0) -> const void* {
    int k = k0 * 32 + kq;
    if (k0 < C0) return (const void*)(xa + (size_t)m * SA + k);
    if (k0 < C1) return (const void*)(xb + (size_t)m * SB + (k - C0 * 32));
    return (const void*)(xc + (size_t)m * SC + (k - C1 * 32));
  };
  float4v aa0,aa1,aa2,aa3,aa4,aa5,aa6,aa7,aa8,aa9,aa10,aa11,aa12,aa13,aa14,aa15,aa16,aa17,aa18,aa19;
  LDC(aa0,sel(f0+0)); LDC(aa1,sel(f0+1)); LDC(aa2,sel(f0+2)); LDC(aa3,sel(f0+3));
  LDC(aa4,sel(f0+4)); LDC(aa5,sel(f0+5)); LDC(aa6,sel(f0+6)); LDC(aa7,sel(f0+7));
  LDC(aa8,sel(f0+8)); LDC(aa9,sel(f0+9)); LDC(aa10,sel(f0+10)); LDC(aa11,sel(f0+11));
  LDC(aa12,sel(f0+12)); LDC(aa13,sel(f0+13)); LDC(aa14,sel(f0+14)); LDC(aa15,sel(f0+15));
  LDC(aa16,sel(f0+16)); LDC(aa17,sel(f0+17)); LDC(aa18,sel(f0+18)); LDC(aa19,sel(f0+19));
  asm volatile("s_waitcnt vmcnt(0)"
    : "+v"(aa0),"+v"(aa1),"+v"(aa2),"+v"(aa3),"+v"(aa4),"+v"(aa5),"+v"(aa6),
      "+v"(aa7),"+v"(aa8),"+v"(aa9),"+v"(aa10),"+v"(aa11),"+v"(aa12),"+v"(aa13),
      "+v"(aa14),"+v"(aa15),"+v"(aa16),"+v"(aa17),"+v"(aa18),"+v"(aa19)
    :: "memory");
  float4v acc = {0.f, 0.f, 0.f, 0.f};
  GMF(0); GMF(1); GMF(2); GMF(3); GMF(4); GMF(5); GMF(6); GMF(7); GMF(8); GMF(9);
  GMF(10); GMF(11); GMF(12); GMF(13); GMF(14); GMF(15); GMF(16); GMF(17); GMF(18); GMF(19);
  return acc;
}

// ---------------------------------------------------------------------------
// frame/stop projection for step ft.  Runs on blocks 32..47 (2 batches each).
__device__ __forceinline__ void frame_phase(const Params& p, int ft, int blk, int tid, float* X)
{
  const int bb0 = (blk - 32) * 2;
  const int slot = ft & 1;
  for (int i = tid; i < 768; i += 512) {
    int bbl = i / 384, r = i - bbl * 384;
    const float* src = (r < 256)
        ? (p.hGf + (size_t)(bb0 + bbl) * 1024 + (size_t)r * 4)
        : (p.ctxf + (size_t)slot * (E * B) + (size_t)(bb0 + bbl) * 512 + (size_t)(r - 256) * 4);
    float4v v = ldc1(src);
    float* dst = X + bbl * 1536 + ((r < 256) ? r * 4 : 1024 + (r - 256) * 4);
    *(float4v*)dst = v;
  }
  __syncthreads();
  if (tid < 324) {
    int bbl = tid / 162, r = tid - bbl * 162, j = r >> 1, half = r & 1;
    const float* w = (j < M) ? (p.frame_W + (size_t)j * 1536 + half * 768)
                             : (p.stop_W + half * 768);
    const float* x = X + bbl * 1536 + half * 768;
    float acc = half ? 0.f : ((j < M) ? p.frame_b[j] : p.stop_b[0]);
    #pragma unroll 4
    for (int k = 0; k < 768; ++k) acc += w[k] * x[k];
    acc += __shfl_down(acc, 1, 64);
    if (half == 0) {
      int b = bb0 + bbl;
      if (j < M) p.out[SPEC_OFF + (size_t)b * TDEC * M + (size_t)ft * M + j] = acc;
      else       p.out[STOP_OFF + (size_t)b * TDEC + ft] = acc;
    }
  }
}

// ---------------------------------------------------------------------------
__global__ void __launch_bounds__(512) persist_kernel(Params p) {
  extern __shared__ char smem[];
  __hip_bfloat16* attw = (__hip_bfloat16*)(smem + LDS_ATTW);
  __hip_bfloat16* genw = (__hip_bfloat16*)(smem + LDS_GENW);
  float* sc   = (float*)(smem + LDS_SC);
  float* sp   = (float*)(smem + LDS_SP);
  float* scm  = (float*)(smem + LDS_SCM);
  float* cAl  = (float*)(smem + LDS_CA);
  float* cGl  = (float*)(smem + LDS_CG);
  // PA-phase scratch sublayout
  float* hq    = sc;                       // [0..1024)
  float* qpart = sc + 1024;                // [1024..1536)
  float* query = sc + 1536;                // [1536..1664)
  float* red   = sc + 1664;                // [1664..1672)
  u16*   Abuf  = (u16*)(smem + LDS_SC + 6784);   // 6656 bf16 (overlaps epart tail; disjoint in time)
  float* epart = sc + 3360;                // [3360..4960)
  float* e_w   = sc + 4960;                // [4960..5160)

  const int tid  = threadIdx.x;
  const int blk  = blockIdx.x;
  const int lane = tid & 63;
  const int wv   = tid >> 6;
  int ep = 0;

  // ============ prolog: pack weight slices into LDS ============
  for (int idx = tid; idx < 56 * 512; idx += 512) {
    int k0 = idx >> 9, e = idx & 511, ln = e >> 3, j = e & 7, r = ln & 15;
    int row = (r & 3) * D + blk * 4 + (r >> 2);
    int k = k0 * 32 + ((ln >> 4) << 3) + j;
    float v = (k < 768) ? p.att_Wih[(size_t)row * 768 + k]
                        : p.att_Whh[(size_t)row * D + (k - 768)];
    attw[idx] = __float2bfloat16(v);
  }
  for (int idx = tid; idx < 80 * 512; idx += 512) {
    int k0 = idx >> 9, e = idx & 511, ln = e >> 3, j = e & 7, r = ln & 15;
    int row = (r & 3) * D + blk * 4 + (r >> 2);
    int k = k0 * 32 + ((ln >> 4) << 3) + j;
    float v = (k < 1536) ? p.gen_Wih[(size_t)row * 1536 + k]
                         : p.gen_Whh[(size_t)row * D + (k - 1536)];
    genw[idx] = __float2bfloat16(v);
  }
  if (tid < 128) { cAl[tid] = 0.f; cGl[tid] = 0.f; }
  for (int i = tid; i < 232; i += 512) { sp[i] = 0.f; scm[i] = 0.f; }
  __syncthreads();

  // ============ pre-phase: att gates for t=0 (ctx=0, hA=0) ============
  {
    const int mt = wv & 1, kqi = wv >> 1;
    const int m = mt * 16 + (lane & 15);
    float4v aA = gemm14<8, 24, 256, 512, 1024>(attw, kqi * 14, p.preB, p.ctxb, p.hAb1, m, lane);
    float* r = sc + ((((0 * 2 + mt) * 4 + kqi) * 64 + lane) << 2);
    r[0] = aA[0]; r[1] = aA[1]; r[2] = aA[2]; r[3] = aA[3];
    __syncthreads();
    if (tid < 128) {
      int dj_l = (tid >> 5) & 3, mm = tid & 31;
      int dj = blk * 4 + dj_l;
      int mt2 = mm >> 4, m2 = mm & 15;
      float g4[4];
      #pragma unroll
      for (int gate = 0; gate < 4; ++gate) {
        int ln = ((m2 >> 2) << 4) | (dj_l * 4 + gate);
        int rg = m2 & 3;
        float s = 0.f;
        #pragma unroll
        for (int kq = 0; kq < 4; ++kq)
          s += sc[((((0 * 2 + mt2) * 4 + kq) * 64 + ln) << 2) + rg];
        g4[gate] = s + p.att_b[gate * D + dj];
      }
      float c  = cAl[dj_l * 32 + mm];
      float cn = sigmoidf(g4[1]) * c + sigmoidf(g4[0]) * tanhf(g4[2]);
      float hn = sigmoidf(g4[3]) * tanhf(cn);
      cAl[dj_l * 32 + mm] = cn;
      stc_u16(p.hAb0 + (size_t)mm * D + dj, f2bf(hn));
    }
  }
  gbar(p.bars, ++ep);

  // ============ main loop ============
  for (int t = 0; t < TDEC; ++t) {
    const u16* hAcur  = (t & 1) ? p.hAb1 : p.hAb0;
    u16*       hAnxt  = (t & 1) ? p.hAb0 : p.hAb1;
    const u16* hGprev = (t & 1) ? p.hGb0 : p.hGb1;
    u16*       hGcur  = (t & 1) ? p.hGb1 : p.hGb0;

    // ---- PA: attention (blocks 0..31) + frame t-1 (blocks 32..47) ----
    if (blk < 32) {
      const int b = blk;
      // 1) stage hA bf16 -> hq fp32
      if (tid < 128) {
        float4v hv = ldc1(hAcur + (size_t)b * 1024 + (size_t)tid * 8);
        short8 hs = __builtin_bit_cast(short8, hv);
        #pragma unroll
        for (int j = 0; j < 8; ++j) hq[tid * 8 + j] = bf2f((u16)hs[j]);
      }
      __syncthreads();
      // 2) query = hA @ Wq.T (bf16 weights, cached)
      {
        const int a = tid >> 2, qk = tid & 3;
        const u16* wrow = p.wqb + (size_t)a * 1024 + qk * 256;
        const float* hh = hq + qk * 256;
        float acc = 0.f;
        #pragma unroll 4
        for (int i = 0; i < 32; ++i) {
          short8 wv8 = *(const short8*)(wrow + i * 8);
          #pragma unroll
          for (int j = 0; j < 8; ++j) acc += bf2f((u16)wv8[j]) * hh[i * 8 + j];
        }
        qpart[tid] = acc;
      }
      __syncthreads();
      if (tid < 128)
        query[tid] = qpart[tid * 4] + qpart[tid * 4 + 1] + qpart[tid * 4 + 2]
                   + qpart[tid * 4 + 3] + p.b_att[tid];
      // 3) location conv as MFMA: lp[tt][a], two passes (wprev, wcum)
      float4v cacc[13];
      #pragma unroll
      for (int i = 0; i < 13; ++i) cacc[i] = (float4v){0.f, 0.f, 0.f, 0.f};
      const int tn = wv, cl = lane & 15, kq8 = (lane >> 4) << 3;
      #pragma unroll
      for (int pass = 0; pass < 2; ++pass) {
        __syncthreads();
        const float* src = pass ? scm : sp;
        for (int i = tid; i < 6656; i += 512) {
          int r = i >> 5, k = i & 31;
          float v = (r < 200 && k < 31) ? src[r + k] : 0.f;
          Abuf[i] = f2bf(v);
        }
        __syncthreads();
        short8 bfrag = *(const short8*)(p.kpk + ((size_t)(pass * 8 + tn) * 64 + lane) * 8);
        #pragma unroll
        for (int tm = 0; tm < 13; ++tm) {
          short8 av = *(const short8*)(Abuf + (size_t)(tm * 16 + cl) * 32 + kq8);
          cacc[tm] = __builtin_amdgcn_mfma_f32_16x16x32_bf16(av, bfrag, cacc[tm], 0, 0, 0);
        }
      }
      // 4) energies: tanh(query + pm + lp) . v_att, partial over 16 a's
      {
        const int a = tn * 16 + cl;
        const float qv = query[a];
        const float vv = p.v_att[a];
        #pragma unroll
        for (int tm = 0; tm < 13; ++tm) {
          #pragma unroll
          for (int i = 0; i < 4; ++i) {
            int tt = tm * 16 + ((lane >> 4) << 2) + i;
            float val = 0.f;
            if (tt < 200)
              val = tanhf(qv + p.pm[((size_t)b * TENC + tt) * A + a] + cacc[tm][i]) * vv;
            val += __shfl_down(val, 8, 16);
            val += __shfl_down(val, 4, 16);
            val += __shfl_down(val, 2, 16);
            val += __shfl_down(val, 1, 16);
            if (cl == 0 && tt < 200) epart[tt * 8 + tn] = val;
          }
        }
      }
      __syncthreads();
      // 5) softmax over 200
      const int len = p.lens[b];
      if (tid < 200) {
        float e = 0.f;
        #pragma unroll
        for (int i = 0; i < 8; ++i) e += epart[tid * 8 + i];
        e_w[tid] = (tid < len) ? e : -1.0e9f;
      }
      __syncthreads();
      float lm = (tid < 200) ? e_w[tid] : -3.0e38f;
      for (int o = 32; o > 0; o >>= 1) lm = fmaxf(lm, __shfl_down(lm, o, 64));
      if (lane == 0) red[wv] = lm;
      __syncthreads();
      float gm = red[0];
      #pragma unroll
      for (int i = 1; i < 8; ++i) gm = fmaxf(gm, red[i]);
      float ls = 0.f;
      float myp = 0.f;
      if (tid < 200) { myp = expf(e_w[tid] - gm); ls = myp; }
      __syncthreads();
      if (tid < 200) e_w[tid] = myp;
      for (int o = 32; o > 0; o >>= 1) ls += __shfl_down(ls, o, 64);
      if (lane == 0) red[wv] = ls;
      __syncthreads();
      float inv = 0.f;
      #pragma unroll
      for (int i = 0; i < 8; ++i) inv += red[i];
      inv = 1.0f / inv;
      __syncthreads();
      if (tid < 200) {
        float wval = e_w[tid] * inv;
        e_w[tid] = wval;
        sp[15 + tid] = wval;
        scm[15 + tid] += wval;
        p.out[ALIGN_OFF + ((size_t)b * TDEC + t) * TENC + tid] = wval;
      }
      __syncthreads();
      // 6) context = w @ enc[b]  (coalesced row reads, L2-warm)
      {
        const float* ebase = p.enc + (size_t)b * TENC * E + tid;
        float acc = 0.f;
        #pragma unroll 4
        for (int tt = 0; tt < 200; ++tt) acc += e_w[tt] * ebase[(size_t)tt * E];
        stc_f32(p.ctxf + (size_t)(t & 1) * (E * B) + (size_t)b * 512 + tid, acc);
        stc_u16(p.ctxb + (size_t)b * 512 + tid, f2bf(acc));
      }
    } else if (blk >= 32 && blk < 48) {
      if (t > 0) frame_phase(p, t - 1, blk, tid, sc);
    }
    gbar(p.bars, ++ep);

    // ---- PG: gen gates t + att gates t+1 (all 256 blocks) ----
    {
      const bool doatt = (t < TDEC - 1);
      const int mt = wv & 1, kqi = wv >> 1;
      const int m = mt * 16 + (lane & 15);
      if (doatt) {
        float4v aA = gemm14<8, 24, 256, 512, 1024>(attw, kqi * 14,
                         p.preB + (size_t)(t + 1) * (B * P), p.ctxb, hAcur, m, lane);
        float* r = sc + ((((0 * 2 + mt) * 4 + kqi) * 64 + lane) << 2);
        r[0] = aA[0]; r[1] = aA[1]; r[2] = aA[2]; r[3] = aA[3];
      }
      {
        float4v aG = gemm20<32, 48, 1024, 512, 1024>(genw, kqi * 20,
                         hAcur, p.ctxb, hGprev, m, lane);
        float* r = sc + ((((1 * 2 + mt) * 4 + kqi) * 64 + lane) << 2);
        r[0] = aG[0]; r[1] = aG[1]; r[2] = aG[2]; r[3] = aG[3];
      }
      __syncthreads();
      if (tid < 256) {
        const int g = tid >> 7, dj_l = (tid >> 5) & 3, mm = tid & 31;
        if (g == 1 || doatt) {
          const int dj = blk * 4 + dj_l;
          const int mt2 = mm >> 4, m2 = mm & 15;
          const float* bias = (g == 0) ? p.att_b : p.gen_b;
          float g4[4];
          #pragma unroll
          for (int gate = 0; gate < 4; ++gate) {
            int ln = ((m2 >> 2) << 4) | (dj_l * 4 + gate);
            int rg = m2 & 3;
            float s = 0.f;
            #pragma unroll
            for (int kq = 0; kq < 4; ++kq)
              s += sc[((((g * 2 + mt2) * 4 + kq) * 64 + ln) << 2) + rg];
            g4[gate] = s + bias[gate * D + dj];
          }
          float* cl2 = (g == 0) ? cAl : cGl;
          float c  = cl2[dj_l * 32 + mm];
          float cn = sigmoidf(g4[1]) * c + sigmoidf(g4[0]) * tanhf(g4[2]);
          float hn = sigmoidf(g4[3]) * tanhf(cn);
          cl2[dj_l * 32 + mm] = cn;
          if (g == 0) {
            stc_u16(hAnxt + (size_t)mm * D + dj, f2bf(hn));
          } else {
            stc_f32(p.hGf + (size_t)mm * 1024 + dj, hn);
            stc_u16(hGcur + (size_t)mm * D + dj, f2bf(hn));
          }
        }
      }
    }
    gbar(p.bars, ++ep);
  }

  // ---- final frame (t = 599) ----
  if (blk >= 32 && blk < 48) frame_phase(p, TDEC - 1, blk, tid, sc);
}

// ---------------------------------------------------------------------------
// Prenet -> preB[t][b][256] bf16
__global__ __launch_bounds__(256) void prenet_kernel(
    const float* __restrict__ target, const float* __restrict__ W1, const float* __restrict__ b1,
    const float* __restrict__ W2, const float* __restrict__ b2, u16* __restrict__ preB)
{
  const int t = blockIdx.x;
  const int tid = threadIdx.x;
  __shared__ float tg[B][M];
  __shared__ float x1[B][P];
  for (int i = tid; i < B * M; i += 256) {
    int b = i / M, m = i - b * M;
    tg[b][m] = (t == 0) ? 0.0f : target[(size_t)b * M * TDEC + (size_t)m * TDEC + (t - 1)];
  }
  __syncthreads();
  for (int i = tid; i < B * P; i += 256) {
    int b = i >> 8, j = i & 255;
    const float* w = W1 + (size_t)j * M;
    float acc = b1[j];
    for (int m = 0; m < M; ++m) acc += w[m] * tg[b][m];
    x1[b][j] = fmaxf(acc, 0.0f);
  }
  __syncthreads();
  for (int i = tid; i < B * P; i += 256) {
    int b = i >> 8, j = i & 255;
    const float* w = W2 + (size_t)j * P;
    float acc = b2[j];
    for (int m = 0; m < P; m += 4)
      acc += w[m]*x1[b][m] + w[m+1]*x1[b][m+1] + w[m+2]*x1[b][m+2] + w[m+3]*x1[b][m+3];
    preB[(size_t)t * (B * P) + (size_t)b * P + j] = f2bf(fmaxf(acc, 0.0f));
  }
}

// ---------------------------------------------------------------------------
__global__ __launch_bounds__(256) void procmem_kernel(
    const float* __restrict__ enc, const float* __restrict__ Wm, float* __restrict__ pm)
{
  const int blk = blockIdx.x;
  const int b = blk >> 3;
  const int t0 = (blk & 7) * 25;
  for (int i = threadIdx.x; i < 25 * A; i += 256) {
    int tl = i >> 7, a = i & 127;
    int t = t0 + tl;
    const float* x = enc + ((size_t)b * TENC + t) * E;
    const float* w = Wm + (size_t)a * E;
    float acc = 0.0f;
    for (int k = 0; k < E; k += 4)
      acc += w[k]*x[k] + w[k+1]*x[k+1] + w[k+2]*x[k+2] + w[k+3]*x[k+3];
    pm[((size_t)b * TENC + t) * A + a] = acc;
  }
}

// ---------------------------------------------------------------------------
// kpk[pass][tn][lane][j] = B-fragment-packed  keff_pass[a][k]
//   a = tn*16 + (lane&15), k = (lane>>4)*8 + j ; tap k<31 else 0
__global__ __launch_bounds__(256) void kpk_kernel(
    const float* __restrict__ lker, const float* __restrict__ Wloc, u16* __restrict__ kpk)
{
  int idx = blockIdx.x * 256 + threadIdx.x;
  if (idx >= 8192) return;
  int j = idx & 7, ln = (idx >> 3) & 63, tn = (idx >> 9) & 7, pass = idx >> 12;
  int a = tn * 16 + (ln & 15);
  int k = ((ln >> 4) << 3) + j;
  float v = 0.f;
  if (k < KC) {
    for (int f = 0; f < LF; ++f)
      v += Wloc[a * LF + f] * lker[f * (2 * KC) + pass * KC + k];
  }
  kpk[idx] = f2bf(v);
}

// ---------------------------------------------------------------------------
__global__ __launch_bounds__(256) void wqpack_kernel(
    const float* __restrict__ Wq, u16* __restrict__ wqb)
{
  int idx = blockIdx.x * 256 + threadIdx.x;
  if (idx < A * D) wqb[idx] = f2bf(Wq[idx]);
}

// ---------------------------------------------------------------------------
extern "C" void kernel_launch(void* const* d_in, const int* in_sizes, int n_in,
                              void* d_out, int out_size, void* d_ws, size_t ws_size,
                              hipStream_t stream)
{
  const float* enc      = (const float*)d_in[0];
  const int*   lens     = (const int*)  d_in[1];
  const float* target   = (const float*)d_in[2];
  const float* pW1      = (const float*)d_in[4];
  const float* pb1      = (const float*)d_in[5];
  const float* pW2      = (const float*)d_in[6];
  const float* pb2      = (const float*)d_in[7];
  const float* att_Wih  = (const float*)d_in[8];
  const float* att_Whh  = (const float*)d_in[9];
  const float* att_b    = (const float*)d_in[10];
  const float* gen_Wih  = (const float*)d_in[11];
  const float* gen_Whh  = (const float*)d_in[12];
  const float* gen_b    = (const float*)d_in[13];
  const float* Wq       = (const float*)d_in[14];
  const float* Wm       = (const float*)d_in[15];
  const float* lker     = (const float*)d_in[16];
  const float* Wloc     = (const float*)d_in[17];
  const float* v_att    = (const float*)d_in[18];
  const float* b_att    = (const float*)d_in[19];
  const float* frame_W  = (const float*)d_in[20];
  const float* frame_b  = (const float*)d_in[21];
  const float* stop_W   = (const float*)d_in[22];
  const float* stop_b   = (const float*)d_in[23];

  float* ws = (float*)d_ws;
  float* st = ws + OFF_ST;

  Params p;
  p.enc = enc; p.lens = lens;
  p.att_Wih = att_Wih; p.att_Whh = att_Whh; p.att_b = att_b;
  p.gen_Wih = gen_Wih; p.gen_Whh = gen_Whh; p.gen_b = gen_b;
  p.v_att = v_att; p.b_att = b_att;
  p.frame_W = frame_W; p.frame_b = frame_b; p.stop_W = stop_W; p.stop_b = stop_b;
  p.pm   = ws + OFF_PM;
  p.preB = (const u16*)(ws + OFF_PREB);
  p.kpk  = (const u16*)(ws + OFF_KPK);
  p.wqb  = (const u16*)(ws + OFF_WQB);
  p.hAb0 = (u16*)(st + ST_HAB0);
  p.hAb1 = (u16*)(st + ST_HAB1);
  p.hGb0 = (u16*)(st + ST_HGB0);
  p.hGb1 = (u16*)(st + ST_HGB1);
  p.ctxb = (u16*)(st + ST_CTXB);
  p.ctxf = st + ST_CTXF;
  p.hGf  = st + ST_HGF;
  p.bars = (unsigned*)(st + ST_BARS);
  p.out  = (float*)d_out;

  hipMemsetAsync((void*)st, 0, N_STATE * sizeof(float), stream);

  kpk_kernel    <<<32, 256, 0, stream>>>(lker, Wloc, (u16*)(ws + OFF_KPK));
  wqpack_kernel <<<512, 256, 0, stream>>>(Wq, (u16*)(ws + OFF_WQB));
  prenet_kernel <<<TDEC, 256, 0, stream>>>(target, pW1, pb1, pW2, pb2, (u16*)(ws + OFF_PREB));
  procmem_kernel<<<256, 256, 0, stream>>>(enc, Wm, ws + OFF_PM);

  hipFuncSetAttribute((const void*)persist_kernel,
                      hipFuncAttributeMaxDynamicSharedMemorySize, SMEM_BYTES);
  persist_kernel<<<256, 512, SMEM_BYTES, stream>>>(p);
}

// Round 5
// 83530.518 us; speedup vs baseline: 2.6864x; 1.0201x over previous
//
#include <hip/hip_runtime.h>
#include <hip/hip_bf16.h>
#include <cstddef>

#define B     32
#define TENC  200
#define E     512
#define D     1024
#define P     256
#define M     80
#define TDEC  600
#define A     128
#define KC    31
#define LF    32

typedef __attribute__((ext_vector_type(8))) short short8;
typedef __attribute__((ext_vector_type(4))) float float4v;
typedef unsigned short u16;

// output offsets (floats)
#define SPEC_OFF  0
#define STOP_OFF  ((size_t)B * TDEC * M)
#define ALIGN_OFF (STOP_OFF + (size_t)B * TDEC)

// ---------------- workspace layout (float units) ----------------
constexpr size_t OFF_PM   = 0;                    // fp32 [b][t][a]   819200
constexpr size_t OFF_PREB = 819200;               // bf16 [t][b][256] 2457600 f
constexpr size_t OFF_KPK  = 3276800;              // bf16 packed keff 8192 -> 4096 f
constexpr size_t OFF_WQB  = 3280896;              // bf16 Wq 131072 -> 65536 f
constexpr size_t OFF_FWB  = 3346432;              // bf16 frame/stop W 81*1536 -> 62208 f
constexpr size_t OFF_ST   = 3408640;
// state region (zeroed each call), float offsets relative to OFF_ST:
constexpr size_t ST_HAB0 = 0;       // bf16 [b][1024] -> 16384 f
constexpr size_t ST_HAB1 = 16384;
constexpr size_t ST_HGB0 = 32768;
constexpr size_t ST_HGB1 = 49152;
constexpr size_t ST_CTXB = 65536;   // bf16 [b][512] -> 8192 f
constexpr size_t ST_CTXF = 73728;   // fp32 2 x [b][512] -> 32768 f
constexpr size_t ST_HGF  = 106496;  // fp32 [b][1024] -> 32768 f
constexpr size_t ST_BARS = 139264;  // 1024 f barrier counters
constexpr size_t N_STATE = 140288;

// ---------------- LDS layout (bytes) ----------------
constexpr int LDS_ATTW = 0;          // 56*512*2  = 57344
constexpr int LDS_GENW = 57344;      // 80*512*2  = 81920
constexpr int LDS_SC   = 139264;     // 5184 floats scratch (20736 B)
constexpr int LDS_SP   = 160000;     // 232 f padded wprev
constexpr int LDS_SCM  = 160928;     // 232 f padded wcum
constexpr int LDS_CA   = 161856;     // 128 f
constexpr int LDS_CG   = 162368;     // 128 f
constexpr int SMEM_BYTES = 162880;   // <= 163840

struct Params {
  const float* enc; const int* lens;
  const float *att_Wih, *att_Whh, *att_b, *gen_Wih, *gen_Whh, *gen_b;
  const float *v_att, *b_att, *frame_b, *stop_b;
  const float *pm;
  const u16 *preB, *kpk, *wqb, *fwb;
  u16 *hAb0, *hAb1, *hGb0, *hGb1, *ctxb;
  float *ctxf, *hGf;
  unsigned* bars;
  float* out;
};

__device__ __forceinline__ float sigmoidf(float x) { return 1.0f / (1.0f + expf(-x)); }
__device__ __forceinline__ u16 f2bf(float x) {
  __hip_bfloat16 h = __float2bfloat16(x);
  return __builtin_bit_cast(u16, h);
}
__device__ __forceinline__ float bf2f(u16 u) {
  unsigned v = ((unsigned)u) << 16;
  return __builtin_bit_cast(float, v);
}

// ---- MALL-coherent access helpers (bypass non-coherent per-XCD L2) ----
#define LDC(r, p) asm volatile("global_load_dwordx4 %0, %1, off sc0 sc1" : "=v"(r) : "v"(p))

__device__ __forceinline__ float4v ldc1(const void* p) {
  float4v r;
  LDC(r, p);
  asm volatile("s_waitcnt vmcnt(0)" : "+v"(r) :: "memory");
  return r;
}
__device__ __forceinline__ void stc_f32(float* p, float v) {
  asm volatile("global_store_dword %0, %1, off sc0 sc1" :: "v"(p), "v"(v) : "memory");
}
__device__ __forceinline__ void stc_u16(u16* p, u16 v) {
  unsigned vv = v;
  asm volatile("global_store_short %0, %1, off sc0 sc1" :: "v"(p), "v"(vv) : "memory");
}

// ---------------------------------------------------------------------------
// grid barrier WITHOUT agent-scope fences (no L2 invalidate).  Inter-block
// data goes through sc0/sc1 (MALL-coherent) accesses.
__device__ __forceinline__ void gbar(unsigned* bars, int ep) {
  __syncthreads();
  if (threadIdx.x == 0) {
    unsigned* grp = bars + ((blockIdx.x >> 4) << 5);
    unsigned old = atomicAdd(grp, 1u);
    if (old + 1u == (unsigned)ep * 16u) atomicAdd(bars + 768, 1u);
    while (__hip_atomic_load(bars + 768, __ATOMIC_RELAXED, __HIP_MEMORY_SCOPE_AGENT)
           < (unsigned)ep * 16u)
      __builtin_amdgcn_s_sleep(2);
  }
  __syncthreads();
}

// ---------------------------------------------------------------------------
#define GMF(i) acc = __builtin_amdgcn_mfma_f32_16x16x32_bf16( \
    __builtin_bit_cast(short8, aa##i), \
    *(const short8*)(lw + ((size_t)(f0 + i) * 512 + (size_t)lane * 8)), acc, 0, 0, 0)

template<int C0, int C1, int SA, int SB, int SC>
__device__ __forceinline__ float4v gemm14(const __hip_bfloat16* lw, int f0,
    const u16* xa, const u16* xb, const u16* xc, int m, int lane)
{
  const int kq = (lane >> 4) << 3;
  auto sel = [&](int k0) -> const void* {
    int k = k0 * 32 + kq;
    if (k0 < C0) return (const void*)(xa + (size_t)m * SA + k);
    if (k0 < C1) return (const void*)(xb + (size_t)m * SB + (k - C0 * 32));
    return (const void*)(xc + (size_t)m * SC + (k - C1 * 32));
  };
  float4v aa0,aa1,aa2,aa3,aa4,aa5,aa6,aa7,aa8,aa9,aa10,aa11,aa12,aa13;
  LDC(aa0,sel(f0+0)); LDC(aa1,sel(f0+1)); LDC(aa2,sel(f0+2)); LDC(aa3,sel(f0+3));
  LDC(aa4,sel(f0+4)); LDC(aa5,sel(f0+5)); LDC(aa6,sel(f0+6)); LDC(aa7,sel(f0+7));
  LDC(aa8,sel(f0+8)); LDC(aa9,sel(f0+9)); LDC(aa10,sel(f0+10)); LDC(aa11,sel(f0+11));
  LDC(aa12,sel(f0+12)); LDC(aa13,sel(f0+13));
  asm volatile("s_waitcnt vmcnt(0)"
    : "+v"(aa0),"+v"(aa1),"+v"(aa2),"+v"(aa3),"+v"(aa4),"+v"(aa5),"+v"(aa6),
      "+v"(aa7),"+v"(aa8),"+v"(aa9),"+v"(aa10),"+v"(aa11),"+v"(aa12),"+v"(aa13)
    :: "memory");
  float4v acc = {0.f, 0.f, 0.f, 0.f};
  GMF(0); GMF(1); GMF(2); GMF(3); GMF(4); GMF(5); GMF(6);
  GMF(7); GMF(8); GMF(9); GMF(10); GMF(11); GMF(12); GMF(13);
  return acc;
}

template<int C0, int C1, int SA, int SB, int SC>
__device__ __forceinline__ float4v gemm20(const __hip_bfloat16* lw, int f0,
    const u16* xa, const u16* xb, const u16* xc, int m, int lane)
{
  const int kq = (lane >> 4) << 3;
  auto sel = [&](int k0) -> const void* {
    int k = k0 * 32 + kq;
    if (k0 < C0) return (const void*)(xa + (size_t)m * SA + k);
    if (k0 < C1) return (const void*)(xb + (size_t)m * SB + (k - C0 * 32));
    return (const void*)(xc + (size_t)m * SC + (k - C1 * 32));
  };
  float4v aa0,aa1,aa2,aa3,aa4,aa5,aa6,aa7,aa8,aa9,aa10,aa11,aa12,aa13,aa14,aa15,aa16,aa17,aa18,aa19;
  LDC(aa0,sel(f0+0)); LDC(aa1,sel(f0+1)); LDC(aa2,sel(f0+2)); LDC(aa3,sel(f0+3));
  LDC(aa4,sel(f0+4)); LDC(aa5,sel(f0+5)); LDC(aa6,sel(f0+6)); LDC(aa7,sel(f0+7));
  LDC(aa8,sel(f0+8)); LDC(aa9,sel(f0+9)); LDC(aa10,sel(f0+10)); LDC(aa11,sel(f0+11));
  LDC(aa12,sel(f0+12)); LDC(aa13,sel(f0+13)); LDC(aa14,sel(f0+14)); LDC(aa15,sel(f0+15));
  LDC(aa16,sel(f0+16)); LDC(aa17,sel(f0+17)); LDC(aa18,sel(f0+18)); LDC(aa19,sel(f0+19));
  asm volatile("s_waitcnt vmcnt(0)"
    : "+v"(aa0),"+v"(aa1),"+v"(aa2),"+v"(aa3),"+v"(aa4),"+v"(aa5),"+v"(aa6),
      "+v"(aa7),"+v"(aa8),"+v"(aa9),"+v"(aa10),"+v"(aa11),"+v"(aa12),"+v"(aa13),
      "+v"(aa14),"+v"(aa15),"+v"(aa16),"+v"(aa17),"+v"(aa18),"+v"(aa19)
    :: "memory");
  float4v acc = {0.f, 0.f, 0.f, 0.f};
  GMF(0); GMF(1); GMF(2); GMF(3); GMF(4); GMF(5); GMF(6); GMF(7); GMF(8); GMF(9);
  GMF(10); GMF(11); GMF(12); GMF(13); GMF(14); GMF(15); GMF(16); GMF(17); GMF(18); GMF(19);
  return acc;
}

// ---------------------------------------------------------------------------
// frame/stop projection for step ft on frame-worker fi (2 batches each).
// bf16 weights (L2-warm), deep-ILP loads.
__device__ __forceinline__ void frame_phase(const Params& p, int ft, int fi, int tid, float* X)
{
  const int bb0 = fi * 2;
  const int slot = ft & 1;
  for (int i = tid; i < 768; i += 512) {
    int bbl = i / 384, r = i - bbl * 384;
    const float* src = (r < 256)
        ? (p.hGf + (size_t)(bb0 + bbl) * 1024 + (size_t)r * 4)
        : (p.ctxf + (size_t)slot * (E * B) + (size_t)(bb0 + bbl) * 512 + (size_t)(r - 256) * 4);
    float4v v = ldc1(src);
    float* dst = X + bbl * 1536 + ((r < 256) ? r * 4 : 1024 + (r - 256) * 4);
    *(float4v*)dst = v;
  }
  __syncthreads();
  if (tid < 324) {
    int bbl = tid / 162, r = tid - bbl * 162, j = r >> 1, half = r & 1;
    const u16* w = p.fwb + (size_t)j * 1536 + half * 768;
    const float* x = X + bbl * 1536 + half * 768;
    float acc = half ? 0.f : ((j < M) ? p.frame_b[j] : p.stop_b[0]);
    #pragma unroll 8
    for (int k8 = 0; k8 < 96; ++k8) {
      short8 wv8 = *(const short8*)(w + k8 * 8);
      #pragma unroll
      for (int jj = 0; jj < 8; ++jj) acc += bf2f((u16)wv8[jj]) * x[k8 * 8 + jj];
    }
    acc += __shfl_down(acc, 1, 64);
    if (half == 0) {
      int b = bb0 + bbl;
      if (j < M) p.out[SPEC_OFF + (size_t)b * TDEC * M + (size_t)ft * M + j] = acc;
      else       p.out[STOP_OFF + (size_t)b * TDEC + ft] = acc;
    }
  }
  __syncthreads();
}

// ---------------------------------------------------------------------------
__global__ void __launch_bounds__(512) persist_kernel(Params p) {
  extern __shared__ char smem[];
  __hip_bfloat16* attw = (__hip_bfloat16*)(smem + LDS_ATTW);
  __hip_bfloat16* genw = (__hip_bfloat16*)(smem + LDS_GENW);
  float* sc   = (float*)(smem + LDS_SC);
  float* sp   = (float*)(smem + LDS_SP);
  float* scm  = (float*)(smem + LDS_SCM);
  float* cAl  = (float*)(smem + LDS_CA);
  float* cGl  = (float*)(smem + LDS_CG);
  // PA-phase scratch sublayout
  float* hq    = sc;                       // [0..1024)
  float* qpart = sc + 1024;                // [1024..1536)
  float* query = sc + 1536;                // [1536..1664)
  float* red   = sc + 1664;                // [1664..1672)
  u16*   Abuf  = (u16*)(smem + LDS_SC + 6784);   // floats [1696..5024), disjoint in time
  float* epart = sc + 3360;                // [3360..4960) (after Abuf use)
  float* e_w   = sc + 4960;                // [4960..5160)

  const int tid  = threadIdx.x;
  const int blk  = blockIdx.x;
  const int lane = tid & 63;
  const int wv   = tid >> 6;
  // XCD-spread role assignment (robust to chunked blk/32 or round-robin blk%8 mapping):
  const int bb = blk >> 3;                               // candidate batch 0..31
  const bool is_att = ((blk & 7) == (bb & 7));           // batch bb -> block 8*bb + (bb&7)
  const int fi = blk >> 3;                               // candidate frame worker
  const bool is_frame = (fi < 16) && ((blk & 7) == ((fi + 4) & 7));
  int ep = 0;

  // ============ prolog: pack weight slices into LDS ============
  for (int idx = tid; idx < 56 * 512; idx += 512) {
    int k0 = idx >> 9, e = idx & 511, ln = e >> 3, j = e & 7, r = ln & 15;
    int row = (r & 3) * D + blk * 4 + (r >> 2);
    int k = k0 * 32 + ((ln >> 4) << 3) + j;
    float v = (k < 768) ? p.att_Wih[(size_t)row * 768 + k]
                        : p.att_Whh[(size_t)row * D + (k - 768)];
    attw[idx] = __float2bfloat16(v);
  }
  for (int idx = tid; idx < 80 * 512; idx += 512) {
    int k0 = idx >> 9, e = idx & 511, ln = e >> 3, j = e & 7, r = ln & 15;
    int row = (r & 3) * D + blk * 4 + (r >> 2);
    int k = k0 * 32 + ((ln >> 4) << 3) + j;
    float v = (k < 1536) ? p.gen_Wih[(size_t)row * 1536 + k]
                         : p.gen_Whh[(size_t)row * D + (k - 1536)];
    genw[idx] = __float2bfloat16(v);
  }
  if (tid < 128) { cAl[tid] = 0.f; cGl[tid] = 0.f; }
  for (int i = tid; i < 232; i += 512) { sp[i] = 0.f; scm[i] = 0.f; }
  __syncthreads();

  // ============ pre-phase: att gates for t=0 (ctx=0, hA=0) ============
  {
    const int mt = wv & 1, kqi = wv >> 1;
    const int m = mt * 16 + (lane & 15);
    float4v aA = gemm14<8, 24, 256, 512, 1024>(attw, kqi * 14, p.preB, p.ctxb, p.hAb1, m, lane);
    float* r = sc + ((((0 * 2 + mt) * 4 + kqi) * 64 + lane) << 2);
    r[0] = aA[0]; r[1] = aA[1]; r[2] = aA[2]; r[3] = aA[3];
    __syncthreads();
    if (tid < 128) {
      int dj_l = (tid >> 5) & 3, mm = tid & 31;
      int dj = blk * 4 + dj_l;
      int mt2 = mm >> 4, m2 = mm & 15;
      float g4[4];
      #pragma unroll
      for (int gate = 0; gate < 4; ++gate) {
        int ln = ((m2 >> 2) << 4) | (dj_l * 4 + gate);
        int rg = m2 & 3;
        float s = 0.f;
        #pragma unroll
        for (int kq = 0; kq < 4; ++kq)
          s += sc[((((0 * 2 + mt2) * 4 + kq) * 64 + ln) << 2) + rg];
        g4[gate] = s + p.att_b[gate * D + dj];
      }
      float c  = cAl[dj_l * 32 + mm];
      float cn = sigmoidf(g4[1]) * c + sigmoidf(g4[0]) * tanhf(g4[2]);
      float hn = sigmoidf(g4[3]) * tanhf(cn);
      cAl[dj_l * 32 + mm] = cn;
      stc_u16(p.hAb0 + (size_t)mm * D + dj, f2bf(hn));
    }
  }
  gbar(p.bars, ++ep);

  // ============ main loop ============
  for (int t = 0; t < TDEC; ++t) {
    const u16* hAcur  = (t & 1) ? p.hAb1 : p.hAb0;
    u16*       hAnxt  = (t & 1) ? p.hAb0 : p.hAb1;
    const u16* hGprev = (t & 1) ? p.hGb0 : p.hGb1;
    u16*       hGcur  = (t & 1) ? p.hGb1 : p.hGb0;

    // ---- PA: attention (32 spread blocks) + frame t-1 (16 spread blocks) ----
    if (is_att) {
      const int b = bb;
      // 1) stage hA bf16 -> hq fp32
      if (tid < 128) {
        float4v hv = ldc1(hAcur + (size_t)b * 1024 + (size_t)tid * 8);
        short8 hs = __builtin_bit_cast(short8, hv);
        #pragma unroll
        for (int j = 0; j < 8; ++j) hq[tid * 8 + j] = bf2f((u16)hs[j]);
      }
      __syncthreads();
      // 2) query = hA @ Wq.T (bf16 weights, L2-warm)
      {
        const int a = tid >> 2, qk = tid & 3;
        const u16* wrow = p.wqb + (size_t)a * 1024 + qk * 256;
        const float* hh = hq + qk * 256;
        float acc = 0.f;
        #pragma unroll 8
        for (int i = 0; i < 32; ++i) {
          short8 wv8 = *(const short8*)(wrow + i * 8);
          #pragma unroll
          for (int j = 0; j < 8; ++j) acc += bf2f((u16)wv8[j]) * hh[i * 8 + j];
        }
        qpart[tid] = acc;
      }
      __syncthreads();
      if (tid < 128)
        query[tid] = qpart[tid * 4] + qpart[tid * 4 + 1] + qpart[tid * 4 + 2]
                   + qpart[tid * 4 + 3] + p.b_att[tid];
      // 3) location conv as MFMA, two passes (wprev, wcum)
      float4v cacc[13];
      #pragma unroll
      for (int i = 0; i < 13; ++i) cacc[i] = (float4v){0.f, 0.f, 0.f, 0.f};
      const int tn = wv, cl = lane & 15, kq8 = (lane >> 4) << 3;
      #pragma unroll
      for (int pass = 0; pass < 2; ++pass) {
        __syncthreads();
        const float* src = pass ? scm : sp;
        for (int i = tid; i < 6656; i += 512) {
          int r = i >> 5, k = i & 31;
          float v = (r < 200 && k < 31) ? src[r + k] : 0.f;
          Abuf[i] = f2bf(v);
        }
        __syncthreads();
        short8 bfrag = *(const short8*)(p.kpk + ((size_t)(pass * 8 + tn) * 64 + lane) * 8);
        #pragma unroll
        for (int tm = 0; tm < 13; ++tm) {
          short8 av = *(const short8*)(Abuf + (size_t)(tm * 16 + cl) * 32 + kq8);
          cacc[tm] = __builtin_amdgcn_mfma_f32_16x16x32_bf16(av, bfrag, cacc[tm], 0, 0, 0);
        }
      }
      // 4) energies
      {
        const int a = tn * 16 + cl;
        const float qv = query[a];
        const float vv = p.v_att[a];
        #pragma unroll
        for (int tm = 0; tm < 13; ++tm) {
          #pragma unroll
          for (int i = 0; i < 4; ++i) {
            int tt = tm * 16 + ((lane >> 4) << 2) + i;
            float val = 0.f;
            if (tt < 200)
              val = tanhf(qv + p.pm[((size_t)b * TENC + tt) * A + a] + cacc[tm][i]) * vv;
            val += __shfl_down(val, 8, 16);
            val += __shfl_down(val, 4, 16);
            val += __shfl_down(val, 2, 16);
            val += __shfl_down(val, 1, 16);
            if (cl == 0 && tt < 200) epart[tt * 8 + tn] = val;
          }
        }
      }
      __syncthreads();
      // 5) softmax over 200
      const int len = p.lens[b];
      if (tid < 200) {
        float e = 0.f;
        #pragma unroll
        for (int i = 0; i < 8; ++i) e += epart[tid * 8 + i];
        e_w[tid] = (tid < len) ? e : -1.0e9f;
      }
      __syncthreads();
      float lm = (tid < 200) ? e_w[tid] : -3.0e38f;
      for (int o = 32; o > 0; o >>= 1) lm = fmaxf(lm, __shfl_down(lm, o, 64));
      if (lane == 0) red[wv] = lm;
      __syncthreads();
      float gm = red[0];
      #pragma unroll
      for (int i = 1; i < 8; ++i) gm = fmaxf(gm, red[i]);
      float ls = 0.f;
      float myp = 0.f;
      if (tid < 200) { myp = expf(e_w[tid] - gm); ls = myp; }
      __syncthreads();
      if (tid < 200) e_w[tid] = myp;
      for (int o = 32; o > 0; o >>= 1) ls += __shfl_down(ls, o, 64);
      if (lane == 0) red[wv] = ls;
      __syncthreads();
      float inv = 0.f;
      #pragma unroll
      for (int i = 0; i < 8; ++i) inv += red[i];
      inv = 1.0f / inv;
      __syncthreads();
      if (tid < 200) {
        float wval = e_w[tid] * inv;
        e_w[tid] = wval;
        sp[15 + tid] = wval;
        scm[15 + tid] += wval;
        p.out[ALIGN_OFF + ((size_t)b * TDEC + t) * TENC + tid] = wval;
      }
      __syncthreads();
      // 6) context = w @ enc[b]  (L2-warm after spreading; deep unroll for ILP)
      {
        const float* ebase = p.enc + (size_t)b * TENC * E + tid;
        float acc = 0.f;
        #pragma unroll 16
        for (int tt = 0; tt < 200; ++tt) acc += e_w[tt] * ebase[(size_t)tt * E];
        stc_f32(p.ctxf + (size_t)(t & 1) * (E * B) + (size_t)b * 512 + tid, acc);
        stc_u16(p.ctxb + (size_t)b * 512 + tid, f2bf(acc));
      }
    } else if (is_frame) {
      if (t > 0) frame_phase(p, t - 1, fi, tid, sc);
    }
    gbar(p.bars, ++ep);

    // ---- PG: gen gates t + att gates t+1 (all 256 blocks) ----
    {
      const bool doatt = (t < TDEC - 1);
      const int mt = wv & 1, kqi = wv >> 1;
      const int m = mt * 16 + (lane & 15);
      if (doatt) {
        float4v aA = gemm14<8, 24, 256, 512, 1024>(attw, kqi * 14,
                         p.preB + (size_t)(t + 1) * (B * P), p.ctxb, hAcur, m, lane);
        float* r = sc + ((((0 * 2 + mt) * 4 + kqi) * 64 + lane) << 2);
        r[0] = aA[0]; r[1] = aA[1]; r[2] = aA[2]; r[3] = aA[3];
      }
      {
        float4v aG = gemm20<32, 48, 1024, 512, 1024>(genw, kqi * 20,
                         hAcur, p.ctxb, hGprev, m, lane);
        float* r = sc + ((((1 * 2 + mt) * 4 + kqi) * 64 + lane) << 2);
        r[0] = aG[0]; r[1] = aG[1]; r[2] = aG[2]; r[3] = aG[3];
      }
      __syncthreads();
      if (tid < 256) {
        const int g = tid >> 7, dj_l = (tid >> 5) & 3, mm = tid & 31;
        if (g == 1 || doatt) {
          const int dj = blk * 4 + dj_l;
          const int mt2 = mm >> 4, m2 = mm & 15;
          const float* bias = (g == 0) ? p.att_b : p.gen_b;
          float g4[4];
          #pragma unroll
          for (int gate = 0; gate < 4; ++gate) {
            int ln = ((m2 >> 2) << 4) | (dj_l * 4 + gate);
            int rg = m2 & 3;
            float s = 0.f;
            #pragma unroll
            for (int kq = 0; kq < 4; ++kq)
              s += sc[((((g * 2 + mt2) * 4 + kq) * 64 + ln) << 2) + rg];
            g4[gate] = s + bias[gate * D + dj];
          }
          float* cl2 = (g == 0) ? cAl : cGl;
          float c  = cl2[dj_l * 32 + mm];
          float cn = sigmoidf(g4[1]) * c + sigmoidf(g4[0]) * tanhf(g4[2]);
          float hn = sigmoidf(g4[3]) * tanhf(cn);
          cl2[dj_l * 32 + mm] = cn;
          if (g == 0) {
            stc_u16(hAnxt + (size_t)mm * D + dj, f2bf(hn));
          } else {
            stc_f32(p.hGf + (size_t)mm * 1024 + dj, hn);
            stc_u16(hGcur + (size_t)mm * D + dj, f2bf(hn));
          }
        }
      }
    }
    gbar(p.bars, ++ep);
  }

  // ---- final frame (t = 599) ----
  if (is_frame) frame_phase(p, TDEC - 1, fi, tid, sc);
}

// ---------------------------------------------------------------------------
// Prenet -> preB[t][b][256] bf16
__global__ __launch_bounds__(256) void prenet_kernel(
    const float* __restrict__ target, const float* __restrict__ W1, const float* __restrict__ b1,
    const float* __restrict__ W2, const float* __restrict__ b2, u16* __restrict__ preB)
{
  const int t = blockIdx.x;
  const int tid = threadIdx.x;
  __shared__ float tg[B][M];
  __shared__ float x1[B][P];
  for (int i = tid; i < B * M; i += 256) {
    int b = i / M, m = i - b * M;
    tg[b][m] = (t == 0) ? 0.0f : target[(size_t)b * M * TDEC + (size_t)m * TDEC + (t - 1)];
  }
  __syncthreads();
  for (int i = tid; i < B * P; i += 256) {
    int b = i >> 8, j = i & 255;
    const float* w = W1 + (size_t)j * M;
    float acc = b1[j];
    for (int m = 0; m < M; ++m) acc += w[m] * tg[b][m];
    x1[b][j] = fmaxf(acc, 0.0f);
  }
  __syncthreads();
  for (int i = tid; i < B * P; i += 256) {
    int b = i >> 8, j = i & 255;
    const float* w = W2 + (size_t)j * P;
    float acc = b2[j];
    for (int m = 0; m < P; m += 4)
      acc += w[m]*x1[b][m] + w[m+1]*x1[b][m+1] + w[m+2]*x1[b][m+2] + w[m+3]*x1[b][m+3];
    preB[(size_t)t * (B * P) + (size_t)b * P + j] = f2bf(fmaxf(acc, 0.0f));
  }
}

// ---------------------------------------------------------------------------
__global__ __launch_bounds__(256) void procmem_kernel(
    const float* __restrict__ enc, const float* __restrict__ Wm, float* __restrict__ pm)
{
  const int blk = blockIdx.x;
  const int b = blk >> 3;
  const int t0 = (blk & 7) * 25;
  for (int i = threadIdx.x; i < 25 * A; i += 256) {
    int tl = i >> 7, a = i & 127;
    int t = t0 + tl;
    const float* x = enc + ((size_t)b * TENC + t) * E;
    const float* w = Wm + (size_t)a * E;
    float acc = 0.0f;
    for (int k = 0; k < E; k += 4)
      acc += w[k]*x[k] + w[k+1]*x[k+1] + w[k+2]*x[k+2] + w[k+3]*x[k+3];
    pm[((size_t)b * TENC + t) * A + a] = acc;
  }
}

// ---------------------------------------------------------------------------
__global__ __launch_bounds__(256) void kpk_kernel(
    const float* __restrict__ lker, const float* __restrict__ Wloc, u16* __restrict__ kpk)
{
  int idx = blockIdx.x * 256 + threadIdx.x;
  if (idx >= 8192) return;
  int j = idx & 7, ln = (idx >> 3) & 63, tn = (idx >> 9) & 7, pass = idx >> 12;
  int a = tn * 16 + (ln & 15);
  int k = ((ln >> 4) << 3) + j;
  float v = 0.f;
  if (k < KC) {
    for (int f = 0; f < LF; ++f)
      v += Wloc[a * LF + f] * lker[f * (2 * KC) + pass * KC + k];
  }
  kpk[idx] = f2bf(v);
}

// ---------------------------------------------------------------------------
__global__ __launch_bounds__(256) void wqpack_kernel(
    const float* __restrict__ Wq, u16* __restrict__ wqb)
{
  int idx = blockIdx.x * 256 + threadIdx.x;
  if (idx < A * D) wqb[idx] = f2bf(Wq[idx]);
}

// ---------------------------------------------------------------------------
// fwb[j][k]: j=0..79 frame rows, j=80 stop row; bf16
__global__ __launch_bounds__(256) void fwpack_kernel(
    const float* __restrict__ frame_W, const float* __restrict__ stop_W, u16* __restrict__ fwb)
{
  int idx = blockIdx.x * 256 + threadIdx.x;
  if (idx >= 81 * 1536) return;
  int j = idx / 1536, k = idx - j * 1536;
  float v = (j < M) ? frame_W[(size_t)j * 1536 + k] : stop_W[k];
  fwb[idx] = f2bf(v);
}

// ---------------------------------------------------------------------------
extern "C" void kernel_launch(void* const* d_in, const int* in_sizes, int n_in,
                              void* d_out, int out_size, void* d_ws, size_t ws_size,
                              hipStream_t stream)
{
  const float* enc      = (const float*)d_in[0];
  const int*   lens     = (const int*)  d_in[1];
  const float* target   = (const float*)d_in[2];
  const float* pW1      = (const float*)d_in[4];
  const float* pb1      = (const float*)d_in[5];
  const float* pW2      = (const float*)d_in[6];
  const float* pb2      = (const float*)d_in[7];
  const float* att_Wih  = (const float*)d_in[8];
  const float* att_Whh  = (const float*)d_in[9];
  const float* att_b    = (const float*)d_in[10];
  const float* gen_Wih  = (const float*)d_in[11];
  const float* gen_Whh  = (const float*)d_in[12];
  const float* gen_b    = (const float*)d_in[13];
  const float* Wq       = (const float*)d_in[14];
  const float* Wm       = (const float*)d_in[15];
  const float* lker     = (const float*)d_in[16];
  const float* Wloc     = (const float*)d_in[17];
  const float* v_att    = (const float*)d_in[18];
  const float* b_att    = (const float*)d_in[19];
  const float* frame_W  = (const float*)d_in[20];
  const float* frame_b  = (const float*)d_in[21];
  const float* stop_W   = (const float*)d_in[22];
  const float* stop_b   = (const float*)d_in[23];

  float* ws = (float*)d_ws;
  float* st = ws + OFF_ST;

  Params p;
  p.enc = enc; p.lens = lens;
  p.att_Wih = att_Wih; p.att_Whh = att_Whh; p.att_b = att_b;
  p.gen_Wih = gen_Wih; p.gen_Whh = gen_Whh; p.gen_b = gen_b;
  p.v_att = v_att; p.b_att = b_att;
  p.frame_b = frame_b; p.stop_b = stop_b;
  p.pm   = ws + OFF_PM;
  p.preB = (const u16*)(ws + OFF_PREB);
  p.kpk  = (const u16*)(ws + OFF_KPK);
  p.wqb  = (const u16*)(ws + OFF_WQB);
  p.fwb  = (const u16*)(ws + OFF_FWB);
  p.hAb0 = (u16*)(st + ST_HAB0);
  p.hAb1 = (u16*)(st + ST_HAB1);
  p.hGb0 = (u16*)(st + ST_HGB0);
  p.hGb1 = (u16*)(st + ST_HGB1);
  p.ctxb = (u16*)(st + ST_CTXB);
  p.ctxf = st + ST_CTXF;
  p.hGf  = st + ST_HGF;
  p.bars = (unsigned*)(st + ST_BARS);
  p.out  = (float*)d_out;

  hipMemsetAsync((void*)st, 0, N_STATE * sizeof(float), stream);

  kpk_kernel    <<<32, 256, 0, stream>>>(lker, Wloc, (u16*)(ws + OFF_KPK));
  wqpack_kernel <<<512, 256, 0, stream>>>(Wq, (u16*)(ws + OFF_WQB));
  fwpack_kernel <<<486, 256, 0, stream>>>(frame_W, stop_W, (u16*)(ws + OFF_FWB));
  prenet_kernel <<<TDEC, 256, 0, stream>>>(target, pW1, pb1, pW2, pb2, (u16*)(ws + OFF_PREB));
  procmem_kernel<<<256, 256, 0, stream>>>(enc, Wm, ws + OFF_PM);

  hipFuncSetAttribute((const void*)persist_kernel,
                      hipFuncAttributeMaxDynamicSharedMemorySize, SMEM_BYTES);
  persist_kernel<<<256, 512, SMEM_BYTES, stream>>>(p);
}